// Round 3
// baseline (4923.355 us; speedup 1.0000x reference)
//
#include <hip/hip_runtime.h>
#include <cstdint>

#define TT 128
#define BB 128
#define HH 512

typedef _Float16 f16;
typedef _Float16 f16x8 __attribute__((ext_vector_type(8)));
typedef float f32x4 __attribute__((ext_vector_type(4)));
typedef unsigned int u32;

// ---- workspace layout (bytes) ----
#define OFF_H0    4096                  // enc layer0 h, [2][128][512] f16 (swizzled rows)
#define OFF_H1    (OFF_H0 + 262144)     // enc layer1 h
#define OFF_D0    (OFF_H1 + 262144)     // dec layer0 h
#define OFF_D1    (OFF_D0 + 262144)     // dec layer1 h
#define OFF_XH    (OFF_D1 + 262144)     // x as f16, [T][128][64], row-swizzled
#define OFF_HS    (OFF_XH + 2097152)    // decoder outputs [T][128][512] f16 (plain)

// ---- LDS layout (bytes) ----
#define L_FC   0          // [64][512] f16 fcW (epilogue only)
#define L_P0   65536      // [32][36] f32 gate preacts layer0 (stride 36: conflict-free)
#define L_P1   70144      // [32][36] f32 gate preacts layer1
#define L_B0   74752      // 32 f32 bias layer0
#define L_B1   74880      // 32 f32 bias layer1
#define L_TOT  75008

#define MFMA16(a,b,c) __builtin_amdgcn_mfma_f32_16x16x32_f16((a),(b),(c),0,0,0)

__device__ __forceinline__ float sigm(float x){ return 1.f/(1.f+__expf(-x)); }
__device__ __forceinline__ float tanhft(float x){ return 1.f - 2.f/(__expf(2.f*x)+1.f); }

// load one B-fragment (8 f16 along K for gate-row srow) from an fp32 weight matrix
__device__ __forceinline__ f16x8 wfrag(const float* __restrict__ src, int K, int srow,
                                       int k, int l8){
  const float* p = src + srow*K + (k<<5) + (l8<<3);
  float4 v0 = *(const float4*)p;
  float4 v1 = *(const float4*)(p+4);
  f16x8 r;
  r[0]=(f16)v0.x; r[1]=(f16)v0.y; r[2]=(f16)v0.z; r[3]=(f16)v0.w;
  r[4]=(f16)v1.x; r[5]=(f16)v1.y; r[6]=(f16)v1.z; r[7]=(f16)v1.w;
  return r;
}

// group-local (64 WG) barrier with bulk-cached-store protocol:
// plain stores (L2) -> syncthreads (vmcnt drain to L2) -> ONE release fence
// (tid0: buffer_wbl2 flushes this XCD L2's dirty lines to coherence point)
// -> relaxed flag store -> wave0 polls peers' flags -> acquire fence
// (buffer_inv) so subsequent plain loads fetch fresh data.
__device__ __forceinline__ void gbar(int* fl, int cg, int tid, int target){
  __syncthreads();
  if (tid == 0){
    __builtin_amdgcn_fence(__ATOMIC_RELEASE, "agent");
    __hip_atomic_store(&fl[cg], target, __ATOMIC_RELAXED, __HIP_MEMORY_SCOPE_AGENT);
  }
  if (tid < 64){
    bool ok = __hip_atomic_load(&fl[tid], __ATOMIC_RELAXED, __HIP_MEMORY_SCOPE_AGENT) >= target;
    while (!__all(ok)){
      __builtin_amdgcn_s_sleep(1);
      ok = __hip_atomic_load(&fl[tid], __ATOMIC_RELAXED, __HIP_MEMORY_SCOPE_AGENT) >= target;
    }
  }
  __syncthreads();
  __builtin_amdgcn_fence(__ATOMIC_ACQUIRE, "agent");
}

// convert x [B][T][64] f32 -> xh [T][128][64] f16, rows XOR-swizzled in 16B blocks
__global__ void cvt_x(const float* __restrict__ x, char* __restrict__ ws){
  int idx = blockIdx.x*256 + threadIdx.x;        // 131072 = T*B*8 units of 16B
  int t = idx >> 10, rem = idx & 1023, b = rem >> 3, blk = rem & 7;
  const float* s = x + (((b<<7) + t)<<6) + (blk<<3);
  float4 v0 = *(const float4*)s, v1 = *(const float4*)(s+4);
  f16x8 h;
  h[0]=(f16)v0.x; h[1]=(f16)v0.y; h[2]=(f16)v0.z; h[3]=(f16)v0.w;
  h[4]=(f16)v1.x; h[5]=(f16)v1.y; h[6]=(f16)v1.z; h[7]=(f16)v1.w;
  int db = blk ^ (b & 7);
  *(f16x8*)(ws + OFF_XH + (((t<<7)+b)<<7) + (db<<4)) = h;
}

__global__ __launch_bounds__(256, 1) void lstm_persist(
    const float* __restrict__ eWih0, const float* __restrict__ eWhh0,
    const float* __restrict__ ebi0,  const float* __restrict__ ebh0,
    const float* __restrict__ eWih1, const float* __restrict__ eWhh1,
    const float* __restrict__ ebi1,  const float* __restrict__ ebh1,
    const float* __restrict__ dWih0, const float* __restrict__ dWhh0,
    const float* __restrict__ dbi0,  const float* __restrict__ dbh0,
    const float* __restrict__ dWih1, const float* __restrict__ dWhh1,
    const float* __restrict__ dbi1,  const float* __restrict__ dbh1,
    const float* __restrict__ fcW,   const float* __restrict__ fcb,
    float* __restrict__ out, char* __restrict__ ws)
{
  __shared__ __align__(16) char lds[L_TOT];
  const int tid  = threadIdx.x;
  const int wg   = blockIdx.x;
  const int g    = wg >> 6;            // batch group (32 rows) - groups independent
  const int cg   = wg & 63;            // column group (8 h-cols = 32 gate-cols)
  const int b0   = g << 5;
  const int lane = tid & 63, wave = tid >> 6;
  const int mi = wave >> 1, ni = wave & 1;       // wave -> 16x16 C tile (2x2)
  const int arow = (mi<<4) + (lane & 15);        // A frag row (batch row in group)
  const int l8   = lane >> 4;                    // which 8-elem k-run (0..3)
  const int klb  = l8 << 4;                      // its byte offset in a 32k chunk
  const int brow = (ni<<4) + (lane & 15);        // B frag row (gate col in WG slice)
  const int srow = ((brow>>3)<<9) + (cg<<3) + (brow&7);  // global gate row
  const int sw   = (arow & 7) << 4;              // row XOR-swizzle for A loads
  const int pcol = brow;
  const int rb = tid >> 3, hcl = tid & 7;        // gate phase: thread = (row, h-col)

  int* flags = (int*)ws + (g<<6);
  char* H0 = ws + OFF_H0;  char* H1 = ws + OFF_H1;
  char* D0 = ws + OFF_D0;  char* D1 = ws + OFF_D1;
  const char* XH = ws + OFF_XH;
  char* HS = ws + OFF_HS;

  float* P0 = (float*)(lds + L_P0); float* P1 = (float*)(lds + L_P1);
  float* B0 = (float*)(lds + L_B0); float* B1 = (float*)(lds + L_B1);

  // per-k swizzled A byte offsets (loop-invariant)
  int o16[16];
#pragma unroll
  for (int k = 0; k < 16; ++k) o16[k] = ((k<<6) + klb) ^ sw;
  const int ox0 = klb ^ sw, ox1 = (64 + klb) ^ sw;

  // ---- encoder weights -> registers (loop-invariant fragments) ----
  f16x8 wA[16], wB[16], wC[16], wX0, wX1;
#pragma unroll
  for (int k = 0; k < 16; ++k){
    wA[k] = wfrag(eWhh0, 512, srow, k, l8);
    wB[k] = wfrag(eWih1, 512, srow, k, l8);
    wC[k] = wfrag(eWhh1, 512, srow, k, l8);
  }
  wX0 = wfrag(eWih0, 64, srow, 0, l8);
  wX1 = wfrag(eWih0, 64, srow, 1, l8);
  if (tid < 32){
    int sr = ((tid>>3)<<9) + (cg<<3) + (tid&7);
    B0[tid] = ebi0[sr] + ebh0[sr];
    B1[tid] = ebi1[sr] + ebh1[sr];
  }
  __syncthreads();

  float c0v = 0.f, c1v = 0.f;
  int bt = 0;

  // ================= encoder: layers 0+1 pipelined, 1 barrier/step =================
  for (int s = 0; s <= TT; ++s){
    const bool d0 = (s < TT), d1 = (s >= 1);
    const char* r0row = H0 + ((s&1)<<17) + ((b0 + arow)<<10);
    const char* r1row = H1 + ((s&1)<<17) + ((b0 + arow)<<10);
    char* W0 = H0 + (((s+1)&1)<<17) + (b0<<10);
    char* W1 = H1 + (((s+1)&1)<<17) + (b0<<10);

    // issue all A loads up-front (global -> VGPR, one exposed latency)
    f16x8 xa0, xa1;
    if (d0){
      const char* xrow = XH + (((s<<7) + b0 + arow)<<7);
      xa0 = *(const f16x8*)(xrow + ox0);
      xa1 = *(const f16x8*)(xrow + ox1);
    }
    f16x8 a0f[16], a1f[16];
#pragma unroll
    for (int k = 0; k < 16; ++k){
      a0f[k] = *(const f16x8*)(r0row + o16[k]);
      a1f[k] = *(const f16x8*)(r1row + o16[k]);
    }

    f32x4 acc0 = {0.f,0.f,0.f,0.f}, acc1 = {0.f,0.f,0.f,0.f};
    if (d0){
      acc0 = MFMA16(xa0, wX0, acc0);
      acc0 = MFMA16(xa1, wX1, acc0);
    }
#pragma unroll
    for (int k = 0; k < 16; ++k){
      acc0 = MFMA16(a0f[k], wA[k], acc0);       // h0[t-1] serves BOTH layers
      acc1 = MFMA16(a0f[k], wB[k], acc1);
      acc1 = MFMA16(a1f[k], wC[k], acc1);
    }

#pragma unroll
    for (int r = 0; r < 4; ++r){               // C layout: col=lane&15, row=(lane>>4)*4+r
      int prow = (mi<<4) + (l8<<2) + r;
      P0[prow*36 + pcol] = acc0[r];
      P1[prow*36 + pcol] = acc1[r];
    }
    __syncthreads();

    if (d0){
      float gi = sigm  (P0[rb*36 +      hcl] + B0[hcl]);
      float gf = sigm  (P0[rb*36 +  8 + hcl] + B0[8+hcl]);
      float gg = tanhft(P0[rb*36 + 16 + hcl] + B0[16+hcl]);
      float go = sigm  (P0[rb*36 + 24 + hcl] + B0[24+hcl]);
      c0v = gf*c0v + gi*gg;
      float h = go * tanhft(c0v);
      union { f16 hf; unsigned short su; } cv; cv.hf = (f16)h;
      u32 other = (u32)__shfl_xor((int)(u32)cv.su, 1, 64);
      if (!(hcl & 1)){
        u32 pk = (u32)cv.su | (other << 16);
        int blk = cg ^ (rb & 7);
        *(u32*)(W0 + (rb<<10) + (blk<<4) + (hcl<<1)) = pk;     // plain cached store
      }
    }
    if (d1){
      float gi = sigm  (P1[rb*36 +      hcl] + B1[hcl]);
      float gf = sigm  (P1[rb*36 +  8 + hcl] + B1[8+hcl]);
      float gg = tanhft(P1[rb*36 + 16 + hcl] + B1[16+hcl]);
      float go = sigm  (P1[rb*36 + 24 + hcl] + B1[24+hcl]);
      c1v = gf*c1v + gi*gg;
      float h = go * tanhft(c1v);
      union { f16 hf; unsigned short su; } cv; cv.hf = (f16)h;
      u32 other = (u32)__shfl_xor((int)(u32)cv.su, 1, 64);
      if (!(hcl & 1)){
        u32 pk = (u32)cv.su | (other << 16);
        int blk = cg ^ (rb & 7);
        *(u32*)(W1 + (rb<<10) + (blk<<4) + (hcl<<1)) = pk;     // plain cached store
      }
    }
    gbar(flags, cg, tid, ++bt);
  }

  // ================= zx = z @ dW_ih0 + biases (one-time, kept in regs) =================
#pragma unroll
  for (int k = 0; k < 16; ++k) wB[k] = wfrag(dWih0, 512, srow, k, l8);  // reuse wB
  f32x4 zx;
  {
    float zb = dbi0[srow] + dbh0[srow];
    zx[0]=zb; zx[1]=zb; zx[2]=zb; zx[3]=zb;
  }
  {
    const char* zrow = H1 + (1<<17) + ((b0 + arow)<<10);  // z = final enc1 h, parity 1
#pragma unroll
    for (int k = 0; k < 16; ++k){
      f16x8 zf = *(const f16x8*)(zrow + o16[k]);
      zx = MFMA16(zf, wB[k], zx);
    }
  }

  // ---- decoder weights -> registers ----
#pragma unroll
  for (int k = 0; k < 16; ++k){
    wA[k] = wfrag(dWhh0, 512, srow, k, l8);
    wB[k] = wfrag(dWih1, 512, srow, k, l8);
    wC[k] = wfrag(dWhh1, 512, srow, k, l8);
  }
  if (tid < 32){
    int sr = ((tid>>3)<<9) + (cg<<3) + (tid&7);
    B1[tid] = dbi1[sr] + dbh1[sr];
  }
  __syncthreads();
  c0v = 0.f; c1v = 0.f;

  // ================= decoder: layers 0+1 pipelined =================
  for (int s = 0; s <= TT; ++s){
    const bool d0 = (s < TT), d1 = (s >= 1);
    const char* r0row = D0 + ((s&1)<<17) + ((b0 + arow)<<10);
    const char* r1row = D1 + ((s&1)<<17) + ((b0 + arow)<<10);
    char* W0 = D0 + (((s+1)&1)<<17) + (b0<<10);
    char* W1 = D1 + (((s+1)&1)<<17) + (b0<<10);

    f16x8 a0f[16], a1f[16];
#pragma unroll
    for (int k = 0; k < 16; ++k){
      a0f[k] = *(const f16x8*)(r0row + o16[k]);
      a1f[k] = *(const f16x8*)(r1row + o16[k]);
    }

    f32x4 acc0 = zx, acc1 = {0.f,0.f,0.f,0.f};  // constant-z product + biases preloaded
#pragma unroll
    for (int k = 0; k < 16; ++k){
      acc0 = MFMA16(a0f[k], wA[k], acc0);
      acc1 = MFMA16(a0f[k], wB[k], acc1);
      acc1 = MFMA16(a1f[k], wC[k], acc1);
    }

#pragma unroll
    for (int r = 0; r < 4; ++r){
      int prow = (mi<<4) + (l8<<2) + r;
      P0[prow*36 + pcol] = acc0[r];
      P1[prow*36 + pcol] = acc1[r];
    }
    __syncthreads();

    if (d0){
      float gi = sigm  (P0[rb*36 +      hcl]);   // biases already inside zx
      float gf = sigm  (P0[rb*36 +  8 + hcl]);
      float gg = tanhft(P0[rb*36 + 16 + hcl]);
      float go = sigm  (P0[rb*36 + 24 + hcl]);
      c0v = gf*c0v + gi*gg;
      float h = go * tanhft(c0v);
      union { f16 hf; unsigned short su; } cv; cv.hf = (f16)h;
      u32 other = (u32)__shfl_xor((int)(u32)cv.su, 1, 64);
      if (!(hcl & 1)){
        u32 pk = (u32)cv.su | (other << 16);
        int blk = cg ^ (rb & 7);
        *(u32*)(W0 + (rb<<10) + (blk<<4) + (hcl<<1)) = pk;     // plain cached store
      }
    }
    if (d1){
      float gi = sigm  (P1[rb*36 +      hcl] + B1[hcl]);
      float gf = sigm  (P1[rb*36 +  8 + hcl] + B1[8+hcl]);
      float gg = tanhft(P1[rb*36 + 16 + hcl] + B1[16+hcl]);
      float go = sigm  (P1[rb*36 + 24 + hcl] + B1[24+hcl]);
      c1v = gf*c1v + gi*gg;
      float h = go * tanhft(c1v);
      union { f16 hf; unsigned short su; } cv; cv.hf = (f16)h;
      u32 other = (u32)__shfl_xor((int)(u32)cv.su, 1, 64);
      if (!(hcl & 1)){
        u32 pk = (u32)cv.su | (other << 16);
        int blk = cg ^ (rb & 7);
        *(u32*)(W1 + (rb<<10) + (blk<<4) + (hcl<<1)) = pk;     // plain cached store
        // plain-layout copy for fc
        *(u32*)(HS + ((((s-1)<<7) + b0 + rb)<<10) + (cg<<4) + (hcl<<1)) = pk;
      }
    }
    gbar(flags, cg, tid, ++bt);
  }

  // ================= fc: out[b][t][:] = HS[t][b][:] @ fcW^T + fcb (group-local) =================
  for (int q = tid; q < 8192; q += 256){        // stage fcW [64][512] -> f16 LDS
    int i = q >> 7, kq = q & 127;
    float4 v = *(const float4*)(fcW + (i<<9) + (kq<<2));
    f16* p = (f16*)(lds + L_FC + (i<<10) + (kq<<3));
    p[0]=(f16)v.x; p[1]=(f16)v.y; p[2]=(f16)v.z; p[3]=(f16)v.w;
  }
  __syncthreads();
  {
    int tl = tid >> 7;
    int t  = (cg<<1) + tl;                      // 64 col-groups x 2 = all 128 timesteps
    int r  = (tid>>2) & 31;
    int iq = tid & 3;
    const char* hsrow = HS + (((t<<7) + b0 + r)<<10);
    float acc[16];
#pragma unroll
    for (int ii = 0; ii < 16; ++ii) acc[ii] = 0.f;
    for (int k8 = 0; k8 < 64; ++k8){
      f16x8 hv = *(const f16x8*)(hsrow + (k8<<4));
#pragma unroll
      for (int ii = 0; ii < 16; ++ii){
        f16x8 wv = *(const f16x8*)(lds + L_FC + (((iq<<4)+ii)<<10) + (k8<<4));
#pragma unroll
        for (int j = 0; j < 8; ++j) acc[ii] += (float)hv[j] * (float)wv[j];
      }
    }
#pragma unroll
    for (int ii = 0; ii < 16; ++ii){
      int i = (iq<<4) + ii;
      out[((((b0+r)<<7) + t)<<6) + i] = acc[ii] + fcb[i];
    }
  }
}

extern "C" void kernel_launch(void* const* d_in, const int* in_sizes, int n_in,
                              void* d_out, int out_size, void* d_ws, size_t ws_size,
                              hipStream_t stream){
  const float* x     = (const float*)d_in[0];
  const float* eWih0 = (const float*)d_in[1];
  const float* eWhh0 = (const float*)d_in[2];
  const float* ebi0  = (const float*)d_in[3];
  const float* ebh0  = (const float*)d_in[4];
  const float* eWih1 = (const float*)d_in[5];
  const float* eWhh1 = (const float*)d_in[6];
  const float* ebi1  = (const float*)d_in[7];
  const float* ebh1  = (const float*)d_in[8];
  const float* dWih0 = (const float*)d_in[9];
  const float* dWhh0 = (const float*)d_in[10];
  const float* dbi0  = (const float*)d_in[11];
  const float* dbh0  = (const float*)d_in[12];
  const float* dWih1 = (const float*)d_in[13];
  const float* dWhh1 = (const float*)d_in[14];
  const float* dbi1  = (const float*)d_in[15];
  const float* dbh1  = (const float*)d_in[16];
  const float* fcW   = (const float*)d_in[17];
  const float* fcb   = (const float*)d_in[18];
  char* ws = (char*)d_ws;

  hipMemsetAsync(d_ws, 0, OFF_XH, stream);       // zero barrier flags + all h double-buffers
  cvt_x<<<512, 256, 0, stream>>>(x, ws);
  lstm_persist<<<256, 256, 0, stream>>>(eWih0,eWhh0,ebi0,ebh0,eWih1,eWhh1,ebi1,ebh1,
                                        dWih0,dWhh0,dbi0,dbh0,dWih1,dWhh1,dbi1,dbh1,
                                        fcW,fcb,(float*)d_out,ws);
}

// Round 4
// 3226.255 us; speedup vs baseline: 1.5260x; 1.5260x over previous
//
#include <hip/hip_runtime.h>
#include <cstdint>

#define TT 128
#define BB 128
#define HH 512

typedef _Float16 f16;
typedef _Float16 f16x8 __attribute__((ext_vector_type(8)));
typedef float f32x4 __attribute__((ext_vector_type(4)));
typedef unsigned int u32;
typedef unsigned long long u64;

// ---- workspace layout (bytes) ----
#define OFF_H0    4096                  // enc layer0 h, [2][128][512] f16 (swizzled rows)
#define OFF_H1    (OFF_H0 + 262144)     // enc layer1 h
#define OFF_D0    (OFF_H1 + 262144)     // dec layer0 h
#define OFF_D1    (OFF_D0 + 262144)     // dec layer1 h
#define OFF_XH    (OFF_D1 + 262144)     // x as f16, [T][128][64], row-swizzled
#define OFF_HS    (OFF_XH + 2097152)    // decoder outputs [T][128][512] f16 (plain)

// ---- LDS layout (bytes) ----
#define L_SA   0          // 32 KB h0 slab  [32 rows][1024B]
#define L_SB   32768      // 32 KB h1 slab
#define L_SX   65536      // 2 x 4KB x-tile double buffer [32 rows][128B]
#define L_P0   73728      // [32][36] f32 gate preacts layer0
#define L_P1   78336      // [32][36] f32 gate preacts layer1
#define L_B0   82944      // 32 f32 bias layer0
#define L_B1   83072      // 32 f32 bias layer1
#define L_TOT  83200
#define L_FC   0          // epilogue overlay: [64][512] f16 fcW (over SA+SB)

#define MFMA16(a,b,c) __builtin_amdgcn_mfma_f32_16x16x32_f16((a),(b),(c),0,0,0)

__device__ __forceinline__ float sigm(float x){ return 1.f/(1.f+__expf(-x)); }
__device__ __forceinline__ float tanhft(float x){ return 1.f - 2.f/(__expf(2.f*x)+1.f); }

// async global->LDS, 16B per lane (dst must be wave-uniform-base + lane*16)
__device__ __forceinline__ void gload_lds16(const char* g, char* l){
  __builtin_amdgcn_global_load_lds(
      (const __attribute__((address_space(1))) unsigned int*)g,
      (__attribute__((address_space(3))) unsigned int*)l, 16, 0, 0);
}

// load one B-fragment (8 f16 along K for gate-row srow) from an fp32 weight matrix
__device__ __forceinline__ f16x8 wfrag(const float* __restrict__ src, int K, int srow,
                                       int k, int l8){
  const float* p = src + srow*K + (k<<5) + (l8<<3);
  float4 v0 = *(const float4*)p;
  float4 v1 = *(const float4*)(p+4);
  f16x8 r;
  r[0]=(f16)v0.x; r[1]=(f16)v0.y; r[2]=(f16)v0.z; r[3]=(f16)v0.w;
  r[4]=(f16)v1.x; r[5]=(f16)v1.y; r[6]=(f16)v1.z; r[7]=(f16)v1.w;
  return r;
}

// R1-proven protocol: atomic h-stores already at LLC (vmcnt drained by syncthreads)
// -> tid0 publishes flag -> wave0 polls peers -> acquire fence invalidates stale
// L1/L2 before slab reload. NO release fence (R3 regression).
__device__ __forceinline__ void gbar(int* fl, int cg, int tid, int target){
  __syncthreads();
  if (tid == 0)
    __hip_atomic_store(&fl[cg], target, __ATOMIC_RELAXED, __HIP_MEMORY_SCOPE_AGENT);
  if (tid < 64){
    bool ok = __hip_atomic_load(&fl[tid], __ATOMIC_RELAXED, __HIP_MEMORY_SCOPE_AGENT) >= target;
    while (!__all(ok)){
      __builtin_amdgcn_s_sleep(1);
      ok = __hip_atomic_load(&fl[tid], __ATOMIC_RELAXED, __HIP_MEMORY_SCOPE_AGENT) >= target;
    }
  }
  __syncthreads();
  __builtin_amdgcn_fence(__ATOMIC_ACQUIRE, "agent");
}

// convert x [B][T][64] f32 -> xh [T][128][64] f16, rows XOR-swizzled in 16B blocks
__global__ void cvt_x(const float* __restrict__ x, char* __restrict__ ws){
  int idx = blockIdx.x*256 + threadIdx.x;        // 131072 = T*B*8 units of 16B
  int t = idx >> 10, rem = idx & 1023, b = rem >> 3, blk = rem & 7;
  const float* s = x + (((b<<7) + t)<<6) + (blk<<3);
  float4 v0 = *(const float4*)s, v1 = *(const float4*)(s+4);
  f16x8 h;
  h[0]=(f16)v0.x; h[1]=(f16)v0.y; h[2]=(f16)v0.z; h[3]=(f16)v0.w;
  h[4]=(f16)v1.x; h[5]=(f16)v1.y; h[6]=(f16)v1.z; h[7]=(f16)v1.w;
  int db = blk ^ (b & 7);
  *(f16x8*)(ws + OFF_XH + (((t<<7)+b)<<7) + (db<<4)) = h;
}

__global__ __launch_bounds__(256, 1) void lstm_persist(
    const float* __restrict__ eWih0, const float* __restrict__ eWhh0,
    const float* __restrict__ ebi0,  const float* __restrict__ ebh0,
    const float* __restrict__ eWih1, const float* __restrict__ eWhh1,
    const float* __restrict__ ebi1,  const float* __restrict__ ebh1,
    const float* __restrict__ dWih0, const float* __restrict__ dWhh0,
    const float* __restrict__ dbi0,  const float* __restrict__ dbh0,
    const float* __restrict__ dWih1, const float* __restrict__ dWhh1,
    const float* __restrict__ dbi1,  const float* __restrict__ dbh1,
    const float* __restrict__ fcW,   const float* __restrict__ fcb,
    float* __restrict__ out, char* __restrict__ ws)
{
  __shared__ __align__(16) char lds[L_TOT];
  const int tid  = threadIdx.x;
  const int wg   = blockIdx.x;
  const int g    = wg >> 6;            // batch group (32 rows) - groups independent
  const int cg   = wg & 63;            // column group (8 h-cols = 32 gate-cols)
  const int b0   = g << 5;
  const int lane = tid & 63, wave = tid >> 6;
  const int mi = wave >> 1, ni = wave & 1;       // wave -> 16x16 C tile (2x2)
  const int arow = (mi<<4) + (lane & 15);        // A frag row (batch row in group)
  const int l8   = lane >> 4;                    // which 8-elem k-run (0..3)
  const int klb  = l8 << 4;                      // its byte offset in a 32k chunk
  const int brow = (ni<<4) + (lane & 15);        // B frag row (gate col in WG slice)
  const int srow = ((brow>>3)<<9) + (cg<<3) + (brow&7);  // global gate row
  const int sw   = (arow & 7) << 4;              // row XOR-swizzle for A reads
  const int pcol = brow;
  const int rb = tid >> 3, hcl = tid & 7;        // gate phase: thread = (row, h-col)

  int* flags = (int*)ws + (g<<6);
  char* H0 = ws + OFF_H0;  char* H1 = ws + OFF_H1;
  char* D0 = ws + OFF_D0;  char* D1 = ws + OFF_D1;
  const char* XH = ws + OFF_XH;
  char* HS = ws + OFF_HS;

  char* SA = lds + L_SA; char* SB = lds + L_SB; char* SX = lds + L_SX;
  float* P0 = (float*)(lds + L_P0); float* P1 = (float*)(lds + L_P1);
  float* B0 = (float*)(lds + L_B0); float* B1 = (float*)(lds + L_B1);

  // per-k swizzled A byte offsets within a 1KB slab row (loop-invariant)
  int o16[16];
#pragma unroll
  for (int k = 0; k < 16; ++k) o16[k] = ((k<<6) + klb) ^ sw;
  const int ox0 = klb ^ sw, ox1 = (64 + klb) ^ sw;
  const int arow_sa = arow << 10;      // slab row byte offset
  const int arow_sx = arow << 7;

  // ---- encoder weights -> registers (loop-invariant fragments) ----
  f16x8 wA[16], wB[16], wC[16], wX0, wX1;
#pragma unroll
  for (int k = 0; k < 16; ++k){
    wA[k] = wfrag(eWhh0, 512, srow, k, l8);
    wB[k] = wfrag(eWih1, 512, srow, k, l8);
    wC[k] = wfrag(eWhh1, 512, srow, k, l8);
  }
  wX0 = wfrag(eWih0, 64, srow, 0, l8);
  wX1 = wfrag(eWih0, 64, srow, 1, l8);
  if (tid < 32){
    int sr = ((tid>>3)<<9) + (cg<<3) + (tid&7);
    B0[tid] = ebi0[sr] + ebh0[sr];
    B1[tid] = ebi1[sr] + ebh1[sr];
  }

  // prefetch x(0) tile into SX[0]
  gload_lds16(XH + ((((0<<7) + b0)<<7) + (tid<<4)), SX + (tid<<4));

  float c0v = 0.f, c1v = 0.f;
  int bt = 0;

  // ================= encoder: layers 0+1 pipelined, 1 barrier/step =================
  for (int s = 0; s <= TT; ++s){
    const bool d0 = (s < TT), d1 = (s >= 1);
    const char* R0 = H0 + ((s&1)<<17) + (b0<<10);   // 32KB slab, h0(s-1)
    const char* R1 = H1 + ((s&1)<<17) + (b0<<10);
    char* W0 = H0 + (((s+1)&1)<<17) + (b0<<10);
    char* W1 = H1 + (((s+1)&1)<<17) + (b0<<10);
    const int xp = (s & 1) << 12;                   // SX parity of current step

    // coalesced slab reload: 16 x global_load_lds (LDS-linear, swizzle preserved)
#pragma unroll
    for (int it = 0; it < 8; ++it){
      gload_lds16(R0 + (it<<12) + (tid<<4), SA + (it<<12) + (tid<<4));
      gload_lds16(R1 + (it<<12) + (tid<<4), SB + (it<<12) + (tid<<4));
    }
    __syncthreads();   // drains vmcnt: slabs + x prefetch complete

    f32x4 acc0 = {0.f,0.f,0.f,0.f}, acc1 = {0.f,0.f,0.f,0.f};
    if (d0){
      f16x8 xa0 = *(const f16x8*)(SX + xp + arow_sx + ox0);
      f16x8 xa1 = *(const f16x8*)(SX + xp + arow_sx + ox1);
      acc0 = MFMA16(xa0, wX0, acc0);
      acc0 = MFMA16(xa1, wX1, acc0);
    }
#pragma unroll
    for (int k = 0; k < 16; ++k){
      f16x8 a0 = *(const f16x8*)(SA + arow_sa + o16[k]);   // h0[t-1] serves BOTH layers
      f16x8 a1 = *(const f16x8*)(SB + arow_sa + o16[k]);
      acc0 = MFMA16(a0, wA[k], acc0);
      acc1 = MFMA16(a0, wB[k], acc1);
      acc1 = MFMA16(a1, wC[k], acc1);
    }

#pragma unroll
    for (int r = 0; r < 4; ++r){               // C layout: col=lane&15, row=(lane>>4)*4+r
      int prow = (mi<<4) + (l8<<2) + r;
      P0[prow*36 + pcol] = acc0[r];
      P1[prow*36 + pcol] = acc1[r];
    }
    __syncthreads();

    if (d0){
      float gi = sigm  (P0[rb*36 +      hcl] + B0[hcl]);
      float gf = sigm  (P0[rb*36 +  8 + hcl] + B0[8+hcl]);
      float gg = tanhft(P0[rb*36 + 16 + hcl] + B0[16+hcl]);
      float go = sigm  (P0[rb*36 + 24 + hcl] + B0[24+hcl]);
      c0v = gf*c0v + gi*gg;
      float h = go * tanhft(c0v);
      union { f16 hf; unsigned short su; } cv; cv.hf = (f16)h;
      u32 pk = (u32)cv.su | (((u32)(unsigned short)__shfl_xor((int)(u32)cv.su, 1, 64)) << 16);
      u32 hi = (u32)__shfl_xor((int)pk, 2, 64);
      if (!(hcl & 3)){
        u64 pk8 = (u64)pk | ((u64)hi << 32);
        int blk = cg ^ (rb & 7);
        __hip_atomic_store((u64*)(W0 + (rb<<10) + (blk<<4) + (hcl<<1)), pk8,
                           __ATOMIC_RELAXED, __HIP_MEMORY_SCOPE_AGENT);
      }
    }
    if (d1){
      float gi = sigm  (P1[rb*36 +      hcl] + B1[hcl]);
      float gf = sigm  (P1[rb*36 +  8 + hcl] + B1[8+hcl]);
      float gg = tanhft(P1[rb*36 + 16 + hcl] + B1[16+hcl]);
      float go = sigm  (P1[rb*36 + 24 + hcl] + B1[24+hcl]);
      c1v = gf*c1v + gi*gg;
      float h = go * tanhft(c1v);
      union { f16 hf; unsigned short su; } cv; cv.hf = (f16)h;
      u32 pk = (u32)cv.su | (((u32)(unsigned short)__shfl_xor((int)(u32)cv.su, 1, 64)) << 16);
      u32 hi = (u32)__shfl_xor((int)pk, 2, 64);
      if (!(hcl & 3)){
        u64 pk8 = (u64)pk | ((u64)hi << 32);
        int blk = cg ^ (rb & 7);
        __hip_atomic_store((u64*)(W1 + (rb<<10) + (blk<<4) + (hcl<<1)), pk8,
                           __ATOMIC_RELAXED, __HIP_MEMORY_SCOPE_AGENT);
      }
    }

    // prefetch next x tile into the other SX parity (independent of h)
    if (s + 1 < TT)
      gload_lds16(XH + (((((s+1)<<7) + b0)<<7) + (tid<<4)), SX + (xp ^ 4096) + (tid<<4));

    gbar(flags, cg, tid, ++bt);
  }

  // ================= zx = z @ dW_ih0 + biases (one-time, kept in regs) =================
#pragma unroll
  for (int it = 0; it < 8; ++it)     // stage z slab (= final enc1 h, parity 1)
    gload_lds16(H1 + (1<<17) + (b0<<10) + (it<<12) + (tid<<4), SA + (it<<12) + (tid<<4));
#pragma unroll
  for (int k = 0; k < 16; ++k) wB[k] = wfrag(dWih0, 512, srow, k, l8);  // reuse wB
  f32x4 zx;
  {
    float zb = dbi0[srow] + dbh0[srow];
    zx[0]=zb; zx[1]=zb; zx[2]=zb; zx[3]=zb;
  }
  __syncthreads();
#pragma unroll
  for (int k = 0; k < 16; ++k){
    f16x8 zf = *(const f16x8*)(SA + arow_sa + o16[k]);
    zx = MFMA16(zf, wB[k], zx);
  }

  // ---- decoder weights -> registers ----
#pragma unroll
  for (int k = 0; k < 16; ++k){
    wA[k] = wfrag(dWhh0, 512, srow, k, l8);
    wB[k] = wfrag(dWih1, 512, srow, k, l8);
    wC[k] = wfrag(dWhh1, 512, srow, k, l8);
  }
  if (tid < 32){
    int sr = ((tid>>3)<<9) + (cg<<3) + (tid&7);
    B1[tid] = dbi1[sr] + dbh1[sr];
  }
  c0v = 0.f; c1v = 0.f;

  // ================= decoder: layers 0+1 pipelined =================
  for (int s = 0; s <= TT; ++s){
    const bool d0 = (s < TT), d1 = (s >= 1);
    const char* R0 = D0 + ((s&1)<<17) + (b0<<10);
    const char* R1 = D1 + ((s&1)<<17) + (b0<<10);
    char* W0 = D0 + (((s+1)&1)<<17) + (b0<<10);
    char* W1 = D1 + (((s+1)&1)<<17) + (b0<<10);

#pragma unroll
    for (int it = 0; it < 8; ++it){
      gload_lds16(R0 + (it<<12) + (tid<<4), SA + (it<<12) + (tid<<4));
      gload_lds16(R1 + (it<<12) + (tid<<4), SB + (it<<12) + (tid<<4));
    }
    __syncthreads();

    f32x4 acc0 = zx, acc1 = {0.f,0.f,0.f,0.f};  // constant-z product + biases preloaded
#pragma unroll
    for (int k = 0; k < 16; ++k){
      f16x8 a0 = *(const f16x8*)(SA + arow_sa + o16[k]);
      f16x8 a1 = *(const f16x8*)(SB + arow_sa + o16[k]);
      acc0 = MFMA16(a0, wA[k], acc0);
      acc1 = MFMA16(a0, wB[k], acc1);
      acc1 = MFMA16(a1, wC[k], acc1);
    }

#pragma unroll
    for (int r = 0; r < 4; ++r){
      int prow = (mi<<4) + (l8<<2) + r;
      P0[prow*36 + pcol] = acc0[r];
      P1[prow*36 + pcol] = acc1[r];
    }
    __syncthreads();

    if (d0){
      float gi = sigm  (P0[rb*36 +      hcl]);   // biases already inside zx
      float gf = sigm  (P0[rb*36 +  8 + hcl]);
      float gg = tanhft(P0[rb*36 + 16 + hcl]);
      float go = sigm  (P0[rb*36 + 24 + hcl]);
      c0v = gf*c0v + gi*gg;
      float h = go * tanhft(c0v);
      union { f16 hf; unsigned short su; } cv; cv.hf = (f16)h;
      u32 pk = (u32)cv.su | (((u32)(unsigned short)__shfl_xor((int)(u32)cv.su, 1, 64)) << 16);
      u32 hi = (u32)__shfl_xor((int)pk, 2, 64);
      if (!(hcl & 3)){
        u64 pk8 = (u64)pk | ((u64)hi << 32);
        int blk = cg ^ (rb & 7);
        __hip_atomic_store((u64*)(W0 + (rb<<10) + (blk<<4) + (hcl<<1)), pk8,
                           __ATOMIC_RELAXED, __HIP_MEMORY_SCOPE_AGENT);
      }
    }
    if (d1){
      float gi = sigm  (P1[rb*36 +      hcl] + B1[hcl]);
      float gf = sigm  (P1[rb*36 +  8 + hcl] + B1[8+hcl]);
      float gg = tanhft(P1[rb*36 + 16 + hcl] + B1[16+hcl]);
      float go = sigm  (P1[rb*36 + 24 + hcl] + B1[24+hcl]);
      c1v = gf*c1v + gi*gg;
      float h = go * tanhft(c1v);
      union { f16 hf; unsigned short su; } cv; cv.hf = (f16)h;
      u32 pk = (u32)cv.su | (((u32)(unsigned short)__shfl_xor((int)(u32)cv.su, 1, 64)) << 16);
      u32 hi = (u32)__shfl_xor((int)pk, 2, 64);
      if (!(hcl & 3)){
        u64 pk8 = (u64)pk | ((u64)hi << 32);
        int blk = cg ^ (rb & 7);
        __hip_atomic_store((u64*)(W1 + (rb<<10) + (blk<<4) + (hcl<<1)), pk8,
                           __ATOMIC_RELAXED, __HIP_MEMORY_SCOPE_AGENT);
        // plain-layout copy for fc (same 8B atomic protocol)
        __hip_atomic_store((u64*)(HS + ((((s-1)<<7) + b0 + rb)<<10) + (cg<<4) + (hcl<<1)), pk8,
                           __ATOMIC_RELAXED, __HIP_MEMORY_SCOPE_AGENT);
      }
    }
    gbar(flags, cg, tid, ++bt);
  }

  // ================= fc: out[b][t][:] = HS[t][b][:] @ fcW^T + fcb (group-local) =================
  for (int q = tid; q < 8192; q += 256){        // stage fcW [64][512] -> f16 LDS
    int i = q >> 7, kq = q & 127;
    float4 v = *(const float4*)(fcW + (i<<9) + (kq<<2));
    f16* p = (f16*)(lds + L_FC + (i<<10) + (kq<<3));
    p[0]=(f16)v.x; p[1]=(f16)v.y; p[2]=(f16)v.z; p[3]=(f16)v.w;
  }
  __syncthreads();
  {
    int tl = tid >> 7;
    int t  = (cg<<1) + tl;                      // 64 col-groups x 2 = all 128 timesteps
    int r  = (tid>>2) & 31;
    int iq = tid & 3;
    const char* hsrow = HS + (((t<<7) + b0 + r)<<10);
    float acc[16];
#pragma unroll
    for (int ii = 0; ii < 16; ++ii) acc[ii] = 0.f;
    for (int k8 = 0; k8 < 64; ++k8){
      f16x8 hv = *(const f16x8*)(hsrow + (k8<<4));
#pragma unroll
      for (int ii = 0; ii < 16; ++ii){
        f16x8 wv = *(const f16x8*)(lds + L_FC + (((iq<<4)+ii)<<10) + (k8<<4));
#pragma unroll
        for (int j = 0; j < 8; ++j) acc[ii] += (float)hv[j] * (float)wv[j];
      }
    }
#pragma unroll
    for (int ii = 0; ii < 16; ++ii){
      int i = (iq<<4) + ii;
      out[((((b0+r)<<7) + t)<<6) + i] = acc[ii] + fcb[i];
    }
  }
}

extern "C" void kernel_launch(void* const* d_in, const int* in_sizes, int n_in,
                              void* d_out, int out_size, void* d_ws, size_t ws_size,
                              hipStream_t stream){
  const float* x     = (const float*)d_in[0];
  const float* eWih0 = (const float*)d_in[1];
  const float* eWhh0 = (const float*)d_in[2];
  const float* ebi0  = (const float*)d_in[3];
  const float* ebh0  = (const float*)d_in[4];
  const float* eWih1 = (const float*)d_in[5];
  const float* eWhh1 = (const float*)d_in[6];
  const float* ebi1  = (const float*)d_in[7];
  const float* ebh1  = (const float*)d_in[8];
  const float* dWih0 = (const float*)d_in[9];
  const float* dWhh0 = (const float*)d_in[10];
  const float* dbi0  = (const float*)d_in[11];
  const float* dbh0  = (const float*)d_in[12];
  const float* dWih1 = (const float*)d_in[13];
  const float* dWhh1 = (const float*)d_in[14];
  const float* dbi1  = (const float*)d_in[15];
  const float* dbh1  = (const float*)d_in[16];
  const float* fcW   = (const float*)d_in[17];
  const float* fcb   = (const float*)d_in[18];
  char* ws = (char*)d_ws;

  hipMemsetAsync(d_ws, 0, OFF_XH, stream);       // zero barrier flags + all h double-buffers
  cvt_x<<<512, 256, 0, stream>>>(x, ws);
  lstm_persist<<<256, 256, 0, stream>>>(eWih0,eWhh0,ebi0,ebh0,eWih1,eWhh1,ebi1,ebh1,
                                        dWih0,dWhh0,dbi0,dbh0,dWih1,dWhh1,dbi1,dbh1,
                                        fcW,fcb,(float*)d_out,ws);
}

// Round 5
// 2879.544 us; speedup vs baseline: 1.7098x; 1.1204x over previous
//
#include <hip/hip_runtime.h>
#include <cstdint>

#define TT 128
#define BB 128
#define HH 512

typedef _Float16 f16;
typedef _Float16 f16x8 __attribute__((ext_vector_type(8)));
typedef float f32x4 __attribute__((ext_vector_type(4)));
typedef unsigned int u32;
typedef unsigned long long u64;

// ---- workspace layout (bytes) ----
// flags: 256 x 64B (one flag per cache line)
#define OFF_H0    16384                 // enc layer0 h: [2 par][4 g][64 cg][32 row][16B]
#define OFF_H1    (OFF_H0 + 262144)
#define OFF_D0    (OFF_H1 + 262144)
#define OFF_D1    (OFF_D0 + 262144)
#define OFF_XH    (OFF_D1 + 262144)     // x f16: [T][4 g][8 blk][32 row][16B]
#define OFF_HS    (OFF_XH + 2097152)    // dec out: [T][64 cg][128 row][16B]

// ---- LDS layout (bytes) ----
#define L_SA   0          // 32 KB h0 slab [64 cg][32 row][16B]
#define L_SB   32768      // 32 KB h1 slab
#define L_SX   65536      // 2 x 4KB x-tile double buffer [8 blk][32 row][16B]
#define L_TOT  73728
#define L_FC   0          // epilogue overlay: [64][512] f16 fcW

#define MFMA16(a,b,c) __builtin_amdgcn_mfma_f32_16x16x32_f16((a),(b),(c),0,0,0)

__device__ __forceinline__ float sigm(float x){ return 1.f/(1.f+__expf(-x)); }
__device__ __forceinline__ float tanhft(float x){ return 1.f - 2.f/(__expf(2.f*x)+1.f); }

// async global->LDS, 16B per lane (dst must be wave-uniform-base + lane*16)
__device__ __forceinline__ void gload_lds16(const char* g, char* l){
  __builtin_amdgcn_global_load_lds(
      (const __attribute__((address_space(1))) unsigned int*)g,
      (__attribute__((address_space(3))) unsigned int*)l, 16, 0, 0);
}

// load one B-fragment (8 f16 along K for gate-row srow) from an fp32 weight matrix
__device__ __forceinline__ f16x8 wfrag(const float* __restrict__ src, int K, int srow,
                                       int k, int l8){
  const float* p = src + srow*K + (k<<5) + (l8<<3);
  float4 v0 = *(const float4*)p;
  float4 v1 = *(const float4*)(p+4);
  f16x8 r;
  r[0]=(f16)v0.x; r[1]=(f16)v0.y; r[2]=(f16)v0.z; r[3]=(f16)v0.w;
  r[4]=(f16)v1.x; r[5]=(f16)v1.y; r[6]=(f16)v1.z; r[7]=(f16)v1.w;
  return r;
}

// group barrier: atomic stores (already at LLC, vmcnt drained by syncthreads) ->
// flag store to its OWN cache line -> wave0 polls 64 line-strided flags -> acquire.
__device__ __forceinline__ void gbar(int* fl, int gb, int cg, int tid, int target){
  __syncthreads();
  if (tid == 0)
    __hip_atomic_store(&fl[(gb+cg)<<4], target, __ATOMIC_RELAXED, __HIP_MEMORY_SCOPE_AGENT);
  if (tid < 64){
    bool ok = __hip_atomic_load(&fl[(gb+tid)<<4], __ATOMIC_RELAXED, __HIP_MEMORY_SCOPE_AGENT) >= target;
    while (!__all(ok)){
      __builtin_amdgcn_s_sleep(1);
      ok = __hip_atomic_load(&fl[(gb+tid)<<4], __ATOMIC_RELAXED, __HIP_MEMORY_SCOPE_AGENT) >= target;
    }
  }
  __syncthreads();
  __builtin_amdgcn_fence(__ATOMIC_ACQUIRE, "agent");
}

// x [B][T][64] f32 -> [T][g][blk][row][16B] f16 with row^((blk&3)<<1) perm
__global__ void cvt_x(const float* __restrict__ x, char* __restrict__ ws){
  int idx = blockIdx.x*256 + threadIdx.x;        // 131072 = T*B*8
  int t = idx >> 10, b = (idx >> 3) & 127, blk = idx & 7;
  const float* s = x + (((b<<7) + t)<<6) + (blk<<3);
  float4 v0 = *(const float4*)s, v1 = *(const float4*)(s+4);
  f16x8 h;
  h[0]=(f16)v0.x; h[1]=(f16)v0.y; h[2]=(f16)v0.z; h[3]=(f16)v0.w;
  h[4]=(f16)v1.x; h[5]=(f16)v1.y; h[6]=(f16)v1.z; h[7]=(f16)v1.w;
  int g = b >> 5, row = b & 31;
  int rp = row ^ ((blk & 3) << 1);
  *(f16x8*)(ws + OFF_XH + (((t<<2)+g)<<12) + (blk<<9) + (rp<<4)) = h;
}

__global__ __launch_bounds__(256, 1) void lstm_persist(
    const float* __restrict__ eWih0, const float* __restrict__ eWhh0,
    const float* __restrict__ ebi0,  const float* __restrict__ ebh0,
    const float* __restrict__ eWih1, const float* __restrict__ eWhh1,
    const float* __restrict__ ebi1,  const float* __restrict__ ebh1,
    const float* __restrict__ dWih0, const float* __restrict__ dWhh0,
    const float* __restrict__ dbi0,  const float* __restrict__ dbh0,
    const float* __restrict__ dWih1, const float* __restrict__ dWhh1,
    const float* __restrict__ dbi1,  const float* __restrict__ dbh1,
    const float* __restrict__ fcW,   const float* __restrict__ fcb,
    float* __restrict__ out, char* __restrict__ ws)
{
  __shared__ __align__(16) char lds[L_TOT];
  const int tid  = threadIdx.x;
  const int wg   = blockIdx.x;
  const int g    = wg >> 6;            // batch group (32 rows) - groups independent
  const int cg   = wg & 63;            // column group (8 h-cols)
  const int b0   = g << 5;
  const int gb   = g << 6;             // flag base
  const int lane = tid & 63, wave = tid >> 6;
  const int mi = wave >> 1, ni = wave & 1;
  const int arow = (mi<<4) + (lane & 15);        // A frag row
  const int l8   = lane >> 4;                    // k-run (0..3)
  // B-row b = lane&15 encodes (hc = b>>2, gate = b&3); wave covers 4 hcols x 4 gates
  const int bq   = lane & 15;
  const int srow = ((bq&3)<<9) + (cg<<3) + (ni<<2) + (bq>>2);   // global gate row
  const int lq   = lane & 3;                     // row-within-quad after transpose
  const int hcc  = (lane >> 2) & 3;              // cell hcol (local to ni half)
  const int row_c = (mi<<4) + ((lane>>4)<<2) + lq;  // cell-owned batch row
  const int cgx  = (cg & 3) << 1;                // row-perm for this WG's store block

  int* flags = (int*)ws;
  char* H0 = ws + OFF_H0;  char* H1 = ws + OFF_H1;
  char* D0 = ws + OFF_D0;  char* D1 = ws + OFF_D1;
  const char* XH = ws + OFF_XH;
  char* HS = ws + OFF_HS;

  char* SA = lds + L_SA; char* SB = lds + L_SB; char* SX = lds + L_SX;

  // A-frag offsets in slab [blk=cg'][row][16B], row perm baked (blk&3 == l8)
  int o16[16];
#pragma unroll
  for (int k = 0; k < 16; ++k)
    o16[k] = (((k<<2)+l8)<<9) + ((arow ^ (l8<<1))<<4);
  const int ox0 = (l8<<9) + ((arow ^ (l8<<1))<<4);
  const int ox1 = ((4+l8)<<9) + ((arow ^ (l8<<1))<<4);
  const int hst = (cg<<9) + ((row_c ^ cgx)<<4) + (ni<<3);   // h store offset

  // ---- encoder weights -> registers ----
  f16x8 wA[16], wB[16], wC[16], wX0, wX1;
#pragma unroll
  for (int k = 0; k < 16; ++k){
    wA[k] = wfrag(eWhh0, 512, srow, k, l8);
    wB[k] = wfrag(eWih1, 512, srow, k, l8);
    wC[k] = wfrag(eWhh1, 512, srow, k, l8);
  }
  wX0 = wfrag(eWih0, 64, srow, 0, l8);
  wX1 = wfrag(eWih0, 64, srow, 1, l8);
  // per-lane cell biases (all 4 gates at this lane's hcol)
  float B0r[4], B1r[4];
#pragma unroll
  for (int e = 0; e < 4; ++e){
    int bi = (e<<9) + (cg<<3) + (ni<<2) + hcc;
    B0r[e] = ebi0[bi] + ebh0[bi];
    B1r[e] = ebi1[bi] + ebh1[bi];
  }

  // quad 4x4 transpose: in: a[r] = preact(col=this lane's (hc,gate), row rg*4+r)
  // out: t[e] = preact(gate e, this lane's hc, row rg*4+lq)
  auto qtr = [&](f32x4 a) -> f32x4 {
    float s0 = __shfl_xor(a[1],1), s1 = __shfl_xor(a[0],1);
    float s2 = __shfl_xor(a[3],1), s3 = __shfl_xor(a[2],1);
    bool o1 = lane & 1;
    float c0 = o1 ? s0 : a[0];
    float c1 = o1 ? a[1] : s1;
    float c2 = o1 ? s2 : a[2];
    float c3 = o1 ? a[3] : s3;
    float u0 = __shfl_xor(c2,2), u1 = __shfl_xor(c3,2);
    float u2 = __shfl_xor(c0,2), u3 = __shfl_xor(c1,2);
    bool o2 = lane & 2;
    f32x4 t;
    t[0] = o2 ? u0 : c0;
    t[1] = o2 ? u1 : c1;
    t[2] = o2 ? c2 : u2;
    t[3] = o2 ? c3 : u3;
    return t;
  };

  // prefetch x(0)
  gload_lds16(XH + ((((0<<2)+g)<<12) + (tid<<4)), SX + (tid<<4));

  float c0v = 0.f, c1v = 0.f;
  int bt = 0;

  // ================= encoder =================
  for (int s = 0; s <= TT; ++s){
    const bool d0 = (s < TT), d1 = (s >= 1);
    const char* R0 = H0 + (((s&1)<<2) + g)*32768;
    const char* R1 = H1 + (((s&1)<<2) + g)*32768;
    char* W0 = H0 + ((((s+1)&1)<<2) + g)*32768;
    char* W1 = H1 + ((((s+1)&1)<<2) + g)*32768;
    const int xp = (s & 1) << 12;

#pragma unroll
    for (int it = 0; it < 8; ++it){
      gload_lds16(R0 + (it<<12) + (tid<<4), SA + (it<<12) + (tid<<4));
      gload_lds16(R1 + (it<<12) + (tid<<4), SB + (it<<12) + (tid<<4));
    }
    if (s + 1 < TT)
      gload_lds16(XH + (((((s+1)<<2)+g)<<12) + (tid<<4)), SX + (xp ^ 4096) + (tid<<4));
    __syncthreads();   // drains vmcnt: slabs (+ prior x prefetch) complete

    f32x4 acc0 = {0.f,0.f,0.f,0.f}, acc1 = {0.f,0.f,0.f,0.f};
    if (d0){
      f16x8 xa0 = *(const f16x8*)(SX + xp + ox0);
      f16x8 xa1 = *(const f16x8*)(SX + xp + ox1);
      acc0 = MFMA16(xa0, wX0, acc0);
      acc0 = MFMA16(xa1, wX1, acc0);
    }
#pragma unroll
    for (int k = 0; k < 16; ++k){
      f16x8 a0 = *(const f16x8*)(SA + o16[k]);
      f16x8 a1 = *(const f16x8*)(SB + o16[k]);
      acc0 = MFMA16(a0, wA[k], acc0);
      acc1 = MFMA16(a0, wB[k], acc1);
      acc1 = MFMA16(a1, wC[k], acc1);
    }

    if (d0){
      f32x4 t = qtr(acc0);
      float gi = sigm(t[0]+B0r[0]), gf = sigm(t[1]+B0r[1]);
      float gg = tanhft(t[2]+B0r[2]), go = sigm(t[3]+B0r[3]);
      c0v = gf*c0v + gi*gg;
      float h = go * tanhft(c0v);
      union { f16 hf; unsigned short su; } cv; cv.hf = (f16)h;
      u32 v = cv.su;
      u32 a4 = (u32)__shfl_xor((int)v, 4);
      u32 p = v | (a4 << 16);                       // valid on even-hc lanes
      u32 q = (u32)__shfl_xor((int)p, 8);
      if (!(lane & 12)){
        u64 pk = (u64)p | ((u64)q << 32);
        __hip_atomic_store((u64*)(W0 + hst), pk,
                           __ATOMIC_RELAXED, __HIP_MEMORY_SCOPE_AGENT);
      }
    }
    if (d1){
      f32x4 t = qtr(acc1);
      float gi = sigm(t[0]+B1r[0]), gf = sigm(t[1]+B1r[1]);
      float gg = tanhft(t[2]+B1r[2]), go = sigm(t[3]+B1r[3]);
      c1v = gf*c1v + gi*gg;
      float h = go * tanhft(c1v);
      union { f16 hf; unsigned short su; } cv; cv.hf = (f16)h;
      u32 v = cv.su;
      u32 a4 = (u32)__shfl_xor((int)v, 4);
      u32 p = v | (a4 << 16);
      u32 q = (u32)__shfl_xor((int)p, 8);
      if (!(lane & 12)){
        u64 pk = (u64)p | ((u64)q << 32);
        __hip_atomic_store((u64*)(W1 + hst), pk,
                           __ATOMIC_RELAXED, __HIP_MEMORY_SCOPE_AGENT);
      }
    }
    gbar(flags, gb, cg, tid, ++bt);
  }

  // ================= zx = z @ dW_ih0 + biases =================
#pragma unroll
  for (int it = 0; it < 8; ++it)     // z slab = final enc1 h (parity 1)
    gload_lds16(H1 + ((1<<2) + g)*32768 + (it<<12) + (tid<<4), SA + (it<<12) + (tid<<4));
#pragma unroll
  for (int k = 0; k < 16; ++k) wB[k] = wfrag(dWih0, 512, srow, k, l8);
  f32x4 zx;
  {
    float zb = dbi0[srow] + dbh0[srow];
    zx[0]=zb; zx[1]=zb; zx[2]=zb; zx[3]=zb;
  }
  __syncthreads();
#pragma unroll
  for (int k = 0; k < 16; ++k)
    zx = MFMA16(*(const f16x8*)(SA + o16[k]), wB[k], zx);

  // ---- decoder weights ----
#pragma unroll
  for (int k = 0; k < 16; ++k){
    wA[k] = wfrag(dWhh0, 512, srow, k, l8);
    wB[k] = wfrag(dWih1, 512, srow, k, l8);
    wC[k] = wfrag(dWhh1, 512, srow, k, l8);
  }
#pragma unroll
  for (int e = 0; e < 4; ++e){
    int bi = (e<<9) + (cg<<3) + (ni<<2) + hcc;
    B1r[e] = dbi1[bi] + dbh1[bi];
  }
  c0v = 0.f; c1v = 0.f;

  // ================= decoder =================
  for (int s = 0; s <= TT; ++s){
    const bool d0 = (s < TT), d1 = (s >= 1);
    const char* R0 = D0 + (((s&1)<<2) + g)*32768;
    const char* R1 = D1 + (((s&1)<<2) + g)*32768;
    char* W0 = D0 + ((((s+1)&1)<<2) + g)*32768;
    char* W1 = D1 + ((((s+1)&1)<<2) + g)*32768;

#pragma unroll
    for (int it = 0; it < 8; ++it){
      gload_lds16(R0 + (it<<12) + (tid<<4), SA + (it<<12) + (tid<<4));
      gload_lds16(R1 + (it<<12) + (tid<<4), SB + (it<<12) + (tid<<4));
    }
    __syncthreads();

    f32x4 acc0 = zx, acc1 = {0.f,0.f,0.f,0.f};
#pragma unroll
    for (int k = 0; k < 16; ++k){
      f16x8 a0 = *(const f16x8*)(SA + o16[k]);
      f16x8 a1 = *(const f16x8*)(SB + o16[k]);
      acc0 = MFMA16(a0, wA[k], acc0);
      acc1 = MFMA16(a0, wB[k], acc1);
      acc1 = MFMA16(a1, wC[k], acc1);
    }

    if (d0){
      f32x4 t = qtr(acc0);
      float gi = sigm(t[0]), gf = sigm(t[1]);      // biases inside zx
      float gg = tanhft(t[2]), go = sigm(t[3]);
      c0v = gf*c0v + gi*gg;
      float h = go * tanhft(c0v);
      union { f16 hf; unsigned short su; } cv; cv.hf = (f16)h;
      u32 v = cv.su;
      u32 a4 = (u32)__shfl_xor((int)v, 4);
      u32 p = v | (a4 << 16);
      u32 q = (u32)__shfl_xor((int)p, 8);
      if (!(lane & 12)){
        u64 pk = (u64)p | ((u64)q << 32);
        __hip_atomic_store((u64*)(W0 + hst), pk,
                           __ATOMIC_RELAXED, __HIP_MEMORY_SCOPE_AGENT);
      }
    }
    if (d1){
      f32x4 t = qtr(acc1);
      float gi = sigm(t[0]+B1r[0]), gf = sigm(t[1]+B1r[1]);
      float gg = tanhft(t[2]+B1r[2]), go = sigm(t[3]+B1r[3]);
      c1v = gf*c1v + gi*gg;
      float h = go * tanhft(c1v);
      union { f16 hf; unsigned short su; } cv; cv.hf = (f16)h;
      u32 v = cv.su;
      u32 a4 = (u32)__shfl_xor((int)v, 4);
      u32 p = v | (a4 << 16);
      u32 q = (u32)__shfl_xor((int)p, 8);
      if (!(lane & 12)){
        u64 pk = (u64)p | ((u64)q << 32);
        __hip_atomic_store((u64*)(W1 + hst), pk,
                           __ATOMIC_RELAXED, __HIP_MEMORY_SCOPE_AGENT);
        // archive for fc: [t][cg][128 row][16B] (line-exclusive per WG)
        __hip_atomic_store((u64*)(HS + ((((s-1)<<6) + cg)<<11) + ((b0 + row_c)<<4) + (ni<<3)), pk,
                           __ATOMIC_RELAXED, __HIP_MEMORY_SCOPE_AGENT);
      }
    }
    gbar(flags, gb, cg, tid, ++bt);
  }

  // ================= fc epilogue =================
  for (int qd = tid; qd < 8192; qd += 256){      // fcW [64][512] -> f16 LDS
    int i = qd >> 7, kq = qd & 127;
    float4 v = *(const float4*)(fcW + (i<<9) + (kq<<2));
    f16* p = (f16*)(lds + L_FC + (i<<10) + (kq<<3));
    p[0]=(f16)v.x; p[1]=(f16)v.y; p[2]=(f16)v.z; p[3]=(f16)v.w;
  }
  __syncthreads();
  {
    int tl = tid >> 7;
    int t  = (cg<<1) + tl;                        // 64 cg x 2 = 128 timesteps
    int r  = (tid>>2) & 31;
    int iq = tid & 3;
    float acc[16];
#pragma unroll
    for (int ii = 0; ii < 16; ++ii) acc[ii] = 0.f;
    for (int k8 = 0; k8 < 64; ++k8){
      f16x8 hv = *(const f16x8*)(HS + (((t<<6)+k8)<<11) + ((b0 + r)<<4));
#pragma unroll
      for (int ii = 0; ii < 16; ++ii){
        f16x8 wv = *(const f16x8*)(lds + L_FC + (((iq<<4)+ii)<<10) + (k8<<4));
#pragma unroll
        for (int j = 0; j < 8; ++j) acc[ii] += (float)hv[j] * (float)wv[j];
      }
    }
#pragma unroll
    for (int ii = 0; ii < 16; ++ii){
      int i = (iq<<4) + ii;
      out[((((b0+r)<<7) + t)<<6) + i] = acc[ii] + fcb[i];
    }
  }
}

extern "C" void kernel_launch(void* const* d_in, const int* in_sizes, int n_in,
                              void* d_out, int out_size, void* d_ws, size_t ws_size,
                              hipStream_t stream){
  const float* x     = (const float*)d_in[0];
  const float* eWih0 = (const float*)d_in[1];
  const float* eWhh0 = (const float*)d_in[2];
  const float* ebi0  = (const float*)d_in[3];
  const float* ebh0  = (const float*)d_in[4];
  const float* eWih1 = (const float*)d_in[5];
  const float* eWhh1 = (const float*)d_in[6];
  const float* ebi1  = (const float*)d_in[7];
  const float* ebh1  = (const float*)d_in[8];
  const float* dWih0 = (const float*)d_in[9];
  const float* dWhh0 = (const float*)d_in[10];
  const float* dbi0  = (const float*)d_in[11];
  const float* dbh0  = (const float*)d_in[12];
  const float* dWih1 = (const float*)d_in[13];
  const float* dWhh1 = (const float*)d_in[14];
  const float* dbi1  = (const float*)d_in[15];
  const float* dbh1  = (const float*)d_in[16];
  const float* fcW   = (const float*)d_in[17];
  const float* fcb   = (const float*)d_in[18];
  char* ws = (char*)d_ws;

  hipMemsetAsync(d_ws, 0, OFF_XH, stream);       // zero flags + all h double-buffers
  cvt_x<<<512, 256, 0, stream>>>(x, ws);
  lstm_persist<<<256, 256, 0, stream>>>(eWih0,eWhh0,ebi0,ebh0,eWih1,eWhh1,ebi1,ebh1,
                                        dWih0,dWhh0,dbi0,dbh0,dWih1,dWhh1,dbi1,dbh1,
                                        fcW,fcb,(float*)d_out,ws);
}

// Round 6
// 1532.803 us; speedup vs baseline: 3.2120x; 1.8786x over previous
//
#include <hip/hip_runtime.h>
#include <cstdint>

#define TT 128

typedef _Float16 f16;
typedef _Float16 f16x8 __attribute__((ext_vector_type(8)));
typedef float f32x4 __attribute__((ext_vector_type(4)));
typedef unsigned int u32;
typedef unsigned long long u64;

// ---- workspace layout (bytes) ----
// flags: 256 x 64B lines
#define OFF_H0    16384                 // h slabs: [2 par][8 g][32 cg][16 row][32B] = 256KB
#define OFF_H1    (OFF_H0 + 262144)
#define OFF_D0    (OFF_H1 + 262144)
#define OFF_D1    (OFF_D0 + 262144)
#define OFF_XH    (OFF_D1 + 262144)     // x f16: [T][8 g][16 row][128B] = 2MB
#define OFF_HS    (OFF_XH + 2097152)    // dec out: [T][128 row][1KB] = 16MB

// ---- LDS ----
#define L_SA   0          // h0 slab staged: [32 cg][16 row][48B] = 24576
#define L_SB   24576      // h1 slab staged
#define L_TOT  65536      // fc overlay [64][1024B] needs 64KB

#define MFMA16(a,b,c) __builtin_amdgcn_mfma_f32_16x16x32_f16((a),(b),(c),0,0,0)

__device__ __forceinline__ float sigm(float x){ return 1.f/(1.f+__expf(-x)); }
__device__ __forceinline__ float tanhft(float x){ return 1.f - 2.f/(__expf(2.f*x)+1.f); }

// one B-fragment (8 f16 along K at gate-row srow) from fp32 weights (plain cached load)
__device__ __forceinline__ f16x8 wfrag(const float* __restrict__ src, int K, int srow,
                                       int k, int j){
  const float* p = src + srow*K + (k<<5) + (j<<3);
  float4 v0 = *(const float4*)p;
  float4 v1 = *(const float4*)(p+4);
  f16x8 r;
  r[0]=(f16)v0.x; r[1]=(f16)v0.y; r[2]=(f16)v0.z; r[3]=(f16)v0.w;
  r[4]=(f16)v1.x; r[5]=(f16)v1.y; r[6]=(f16)v1.z; r[7]=(f16)v1.w;
  return r;
}

// stage one 16KB h slab (global [32cg][16row][32B], written by agent atomics) into
// LDS [32cg][16row][48B] via agent-relaxed atomic b64 loads (coherent, no fence).
__device__ __forceinline__ void stage1(const char* R, char* S, int tid){
  const int cgs = tid >> 3, rr = (tid & 7) << 1;
  const char* gp = R + cgs*512 + rr*32;
  char* sp = S + cgs*768 + rr*48;
  u64 t0[8];
#pragma unroll
  for (int e = 0; e < 2; ++e)
#pragma unroll
    for (int i = 0; i < 4; ++i)
      t0[e*4+i] = __hip_atomic_load((const u64*)(gp + e*32 + i*8),
                                    __ATOMIC_RELAXED, __HIP_MEMORY_SCOPE_AGENT);
#pragma unroll
  for (int e = 0; e < 2; ++e)
#pragma unroll
    for (int i = 0; i < 4; ++i)
      *(u64*)(sp + e*48 + i*8) = t0[e*4+i];
}

__device__ __forceinline__ void stage2(const char* R0, const char* R1,
                                       char* SA, char* SB, int tid){
  const int cgs = tid >> 3, rr = (tid & 7) << 1;
  const char* g0 = R0 + cgs*512 + rr*32;
  const char* g1 = R1 + cgs*512 + rr*32;
  char* s0 = SA + cgs*768 + rr*48;
  char* s1 = SB + cgs*768 + rr*48;
  u64 t0[8], t1[8];
#pragma unroll
  for (int e = 0; e < 2; ++e)
#pragma unroll
    for (int i = 0; i < 4; ++i)
      t0[e*4+i] = __hip_atomic_load((const u64*)(g0 + e*32 + i*8),
                                    __ATOMIC_RELAXED, __HIP_MEMORY_SCOPE_AGENT);
#pragma unroll
  for (int e = 0; e < 2; ++e)
#pragma unroll
    for (int i = 0; i < 4; ++i)
      t1[e*4+i] = __hip_atomic_load((const u64*)(g1 + e*32 + i*8),
                                    __ATOMIC_RELAXED, __HIP_MEMORY_SCOPE_AGENT);
#pragma unroll
  for (int e = 0; e < 2; ++e)
#pragma unroll
    for (int i = 0; i < 4; ++i)
      *(u64*)(s0 + e*48 + i*8) = t0[e*4+i];
#pragma unroll
  for (int e = 0; e < 2; ++e)
#pragma unroll
    for (int i = 0; i < 4; ++i)
      *(u64*)(s1 + e*48 + i*8) = t1[e*4+i];
}

// group barrier (32 WGs), NO acquire fence: syncthreads drains vmcnt (h atomics at
// LLC) -> flag publish -> poll -> syncthreads. Data reads are atomic => coherent.
__device__ __forceinline__ void gbar(int* fl, int g, int cg, int tid, int target){
  __syncthreads();
  if (tid == 0)
    __hip_atomic_store(&fl[((g<<5)+cg)<<4], target,
                       __ATOMIC_RELAXED, __HIP_MEMORY_SCOPE_AGENT);
  if (tid < 64){
    int idx = ((g<<5) + (tid & 31)) << 4;
    bool ok = __hip_atomic_load(&fl[idx], __ATOMIC_RELAXED, __HIP_MEMORY_SCOPE_AGENT) >= target;
    while (!__all(ok)){
      __builtin_amdgcn_s_sleep(1);
      ok = __hip_atomic_load(&fl[idx], __ATOMIC_RELAXED, __HIP_MEMORY_SCOPE_AGENT) >= target;
    }
  }
  __syncthreads();
}

// x [B][T][64] f32 -> [T][g 8][row 16][128B] f16
__global__ void cvt_x(const float* __restrict__ x, char* __restrict__ ws){
  int i = blockIdx.x*256 + threadIdx.x;          // 65536 threads, 16 f32 each
  int p = i & 3, b = (i >> 2) & 127, t = i >> 9;
  const float* s = x + (((b<<7) + t)<<6) + (p<<4);
  float4 v0 = *(const float4*)s,     v1 = *(const float4*)(s+4);
  float4 v2 = *(const float4*)(s+8), v3 = *(const float4*)(s+12);
  f16x8 h0, h1;
  h0[0]=(f16)v0.x; h0[1]=(f16)v0.y; h0[2]=(f16)v0.z; h0[3]=(f16)v0.w;
  h0[4]=(f16)v1.x; h0[5]=(f16)v1.y; h0[6]=(f16)v1.z; h0[7]=(f16)v1.w;
  h1[0]=(f16)v2.x; h1[1]=(f16)v2.y; h1[2]=(f16)v2.z; h1[3]=(f16)v2.w;
  h1[4]=(f16)v3.x; h1[5]=(f16)v3.y; h1[6]=(f16)v3.z; h1[7]=(f16)v3.w;
  char* d = ws + OFF_XH + ((((t<<3) + (b>>4))<<4) + (b&15))*128 + (p<<5);
  *(f16x8*)d = h0;
  *(f16x8*)(d+16) = h1;
}

__global__ __launch_bounds__(256, 1) void lstm_persist(
    const float* __restrict__ eWih0, const float* __restrict__ eWhh0,
    const float* __restrict__ ebi0,  const float* __restrict__ ebh0,
    const float* __restrict__ eWih1, const float* __restrict__ eWhh1,
    const float* __restrict__ ebi1,  const float* __restrict__ ebh1,
    const float* __restrict__ dWih0, const float* __restrict__ dWhh0,
    const float* __restrict__ dbi0,  const float* __restrict__ dbh0,
    const float* __restrict__ dWih1, const float* __restrict__ dWhh1,
    const float* __restrict__ dbi1,  const float* __restrict__ dbh1,
    const float* __restrict__ fcW,   const float* __restrict__ fcb,
    float* __restrict__ out, char* __restrict__ ws)
{
  __shared__ __align__(16) char lds[L_TOT];
  const int tid  = threadIdx.x;
  const int wg   = blockIdx.x;
  const int g    = wg & 7;             // batch group (16 rows); bid&7 aims at XCD-locality
  const int cg   = wg >> 3;            // column group (16 hcols = 64 gate cols)
  const int b0   = g << 4;
  const int lane = tid & 63, w = tid >> 6;       // 4 waves, wave w owns gcols w*4hc..
  const int j    = lane >> 4;                    // k-run (0..3)
  const int arow = lane & 15;                    // A row
  const int bq   = lane & 15;                    // B row: (hc local = bq>>2, gate = bq&3)
  const int srow = ((bq&3)<<9) + (cg<<4) + (w<<2) + (bq>>2);   // global gate row
  const int lq   = lane & 3;
  const int hcc  = (lane >> 2) & 3;              // cell hcol within wave quad-group
  const int row_c = ((lane>>4)<<2) + lq;         // cell-owned batch row (0..15)

  int* flags = (int*)ws;
  char* H0 = ws + OFF_H0;  char* H1 = ws + OFF_H1;
  char* D0 = ws + OFF_D0;  char* D1 = ws + OFF_D1;
  const char* XH = ws + OFF_XH;
  char* HS = ws + OFF_HS;
  char* SA = lds + L_SA; char* SB = lds + L_SB;

  // A-frag LDS base: [cg' = kk*2 + (j>>1)][arow][ (j&1)*16 ], strides 768/48
  const int abase = ((j>>1)*768) + arow*48 + ((j&1)<<4);
  // h store offset within slab: [cg][row][32B], wave piece at w*8
  const int hst = cg*512 + row_c*32 + (w<<3);

  // ---- encoder weights -> registers (compile-time-indexed arrays) ----
  f16x8 wA[16], wB[16], wC[16], wX0, wX1;
#pragma unroll
  for (int k = 0; k < 16; ++k){
    wA[k] = wfrag(eWhh0, 512, srow, k, j);
    wB[k] = wfrag(eWih1, 512, srow, k, j);
    wC[k] = wfrag(eWhh1, 512, srow, k, j);
  }
  wX0 = wfrag(eWih0, 64, srow, 0, j);
  wX1 = wfrag(eWih0, 64, srow, 1, j);
  float B0r[4], B1r[4];
#pragma unroll
  for (int e = 0; e < 4; ++e){
    int bi = (e<<9) + (cg<<4) + (w<<2) + hcc;
    B0r[e] = ebi0[bi] + ebh0[bi];
    B1r[e] = ebi1[bi] + ebh1[bi];
  }

  // quad 4x4 transpose: a[r]=preact(col=(hcc,gate) of this lane, row rg*4+r)
  // -> t[e]=preact(gate e, hcc, row rg*4+lq)
  auto qtr = [&](f32x4 a) -> f32x4 {
    float s0 = __shfl_xor(a[1],1), s1 = __shfl_xor(a[0],1);
    float s2 = __shfl_xor(a[3],1), s3 = __shfl_xor(a[2],1);
    bool o1 = lane & 1;
    float c0 = o1 ? s0 : a[0];
    float c1 = o1 ? a[1] : s1;
    float c2 = o1 ? s2 : a[2];
    float c3 = o1 ? a[3] : s3;
    float u0 = __shfl_xor(c2,2), u1 = __shfl_xor(c3,2);
    float u2 = __shfl_xor(c0,2), u3 = __shfl_xor(c1,2);
    bool o2 = lane & 2;
    f32x4 t;
    t[0] = o2 ? u0 : c0;
    t[1] = o2 ? u1 : c1;
    t[2] = o2 ? c2 : u2;
    t[3] = o2 ? c3 : u3;
    return t;
  };

  float c0v = 0.f, c1v = 0.f;
  int bt = 0;

  // ================= encoder: layers 0+1 pipelined, 1 barrier/step =================
  for (int s = 0; s <= TT; ++s){
    const bool d0 = (s < TT), d1 = (s >= 1);
    const char* R0 = H0 + (((s&1)<<3) + g)*16384;
    const char* R1 = H1 + (((s&1)<<3) + g)*16384;
    char* W0 = H0 + ((((s+1)&1)<<3) + g)*16384;
    char* W1 = H1 + ((((s+1)&1)<<3) + g)*16384;

    stage2(R0, R1, SA, SB, tid);      // coherent atomic loads -> LDS
    f16x8 xa0, xa1;
    if (d0){
      const char* xg = XH + (((s<<3) + g)<<11) + arow*128 + (j<<4);
      xa0 = *(const f16x8*)(xg);       // plain cached loads (x is read-only)
      xa1 = *(const f16x8*)(xg + 64);
    }
    __syncthreads();

    f32x4 acc0 = {0.f,0.f,0.f,0.f}, acc1 = {0.f,0.f,0.f,0.f};
    if (d0){
      acc0 = MFMA16(xa0, wX0, acc0);
      acc0 = MFMA16(xa1, wX1, acc0);
    }
#pragma unroll
    for (int k = 0; k < 16; ++k){
      f16x8 a0 = *(const f16x8*)(SA + k*1536 + abase);   // h0 serves BOTH layers
      f16x8 a1 = *(const f16x8*)(SB + k*1536 + abase);
      acc0 = MFMA16(a0, wA[k], acc0);
      acc1 = MFMA16(a0, wB[k], acc1);
      acc1 = MFMA16(a1, wC[k], acc1);
    }

    if (d0){
      f32x4 t = qtr(acc0);
      float gi = sigm(t[0]+B0r[0]), gf = sigm(t[1]+B0r[1]);
      float gg = tanhft(t[2]+B0r[2]), go = sigm(t[3]+B0r[3]);
      c0v = gf*c0v + gi*gg;
      float h = go * tanhft(c0v);
      union { f16 hf; unsigned short su; } cv; cv.hf = (f16)h;
      u32 v = cv.su;
      u32 p = v | (((u32)(unsigned short)__shfl_xor((int)v, 4)) << 16);
      u32 q = (u32)__shfl_xor((int)p, 8);
      if (!(lane & 12)){
        u64 pk = (u64)p | ((u64)q << 32);
        __hip_atomic_store((u64*)(W0 + hst), pk,
                           __ATOMIC_RELAXED, __HIP_MEMORY_SCOPE_AGENT);
      }
    }
    if (d1){
      f32x4 t = qtr(acc1);
      float gi = sigm(t[0]+B1r[0]), gf = sigm(t[1]+B1r[1]);
      float gg = tanhft(t[2]+B1r[2]), go = sigm(t[3]+B1r[3]);
      c1v = gf*c1v + gi*gg;
      float h = go * tanhft(c1v);
      union { f16 hf; unsigned short su; } cv; cv.hf = (f16)h;
      u32 v = cv.su;
      u32 p = v | (((u32)(unsigned short)__shfl_xor((int)v, 4)) << 16);
      u32 q = (u32)__shfl_xor((int)p, 8);
      if (!(lane & 12)){
        u64 pk = (u64)p | ((u64)q << 32);
        __hip_atomic_store((u64*)(W1 + hst), pk,
                           __ATOMIC_RELAXED, __HIP_MEMORY_SCOPE_AGENT);
      }
    }
    gbar(flags, g, cg, tid, ++bt);
  }

  // ================= zx = z @ dW_ih0 + biases (one-time) =================
  f32x4 zx;
  {
    stage1(H1 + (8 + g)*16384, SA, tid);        // z = final enc1 h, parity 1
    f16x8 wZ[16];
#pragma unroll
    for (int k = 0; k < 16; ++k) wZ[k] = wfrag(dWih0, 512, srow, k, j);
    float zb = dbi0[srow] + dbh0[srow];
    zx[0]=zb; zx[1]=zb; zx[2]=zb; zx[3]=zb;
    __syncthreads();
#pragma unroll
    for (int k = 0; k < 16; ++k)
      zx = MFMA16(*(const f16x8*)(SA + k*1536 + abase), wZ[k], zx);
  }

  // ---- decoder weights ----
#pragma unroll
  for (int k = 0; k < 16; ++k){
    wA[k] = wfrag(dWhh0, 512, srow, k, j);
    wB[k] = wfrag(dWih1, 512, srow, k, j);
    wC[k] = wfrag(dWhh1, 512, srow, k, j);
  }
#pragma unroll
  for (int e = 0; e < 4; ++e){
    int bi = (e<<9) + (cg<<4) + (w<<2) + hcc;
    B1r[e] = dbi1[bi] + dbh1[bi];
  }
  c0v = 0.f; c1v = 0.f;

  // ================= decoder =================
  for (int s = 0; s <= TT; ++s){
    const bool d0 = (s < TT), d1 = (s >= 1);
    const char* R0 = D0 + (((s&1)<<3) + g)*16384;
    const char* R1 = D1 + (((s&1)<<3) + g)*16384;
    char* W0 = D0 + ((((s+1)&1)<<3) + g)*16384;
    char* W1 = D1 + ((((s+1)&1)<<3) + g)*16384;

    stage2(R0, R1, SA, SB, tid);
    __syncthreads();

    f32x4 acc0 = zx, acc1 = {0.f,0.f,0.f,0.f};
#pragma unroll
    for (int k = 0; k < 16; ++k){
      f16x8 a0 = *(const f16x8*)(SA + k*1536 + abase);
      f16x8 a1 = *(const f16x8*)(SB + k*1536 + abase);
      acc0 = MFMA16(a0, wA[k], acc0);
      acc1 = MFMA16(a0, wB[k], acc1);
      acc1 = MFMA16(a1, wC[k], acc1);
    }

    if (d0){
      f32x4 t = qtr(acc0);
      float gi = sigm(t[0]), gf = sigm(t[1]);    // biases folded into zx
      float gg = tanhft(t[2]), go = sigm(t[3]);
      c0v = gf*c0v + gi*gg;
      float h = go * tanhft(c0v);
      union { f16 hf; unsigned short su; } cv; cv.hf = (f16)h;
      u32 v = cv.su;
      u32 p = v | (((u32)(unsigned short)__shfl_xor((int)v, 4)) << 16);
      u32 q = (u32)__shfl_xor((int)p, 8);
      if (!(lane & 12)){
        u64 pk = (u64)p | ((u64)q << 32);
        __hip_atomic_store((u64*)(W0 + hst), pk,
                           __ATOMIC_RELAXED, __HIP_MEMORY_SCOPE_AGENT);
      }
    }
    if (d1){
      f32x4 t = qtr(acc1);
      float gi = sigm(t[0]+B1r[0]), gf = sigm(t[1]+B1r[1]);
      float gg = tanhft(t[2]+B1r[2]), go = sigm(t[3]+B1r[3]);
      c1v = gf*c1v + gi*gg;
      float h = go * tanhft(c1v);
      union { f16 hf; unsigned short su; } cv; cv.hf = (f16)h;
      u32 v = cv.su;
      u32 p = v | (((u32)(unsigned short)__shfl_xor((int)v, 4)) << 16);
      u32 q = (u32)__shfl_xor((int)p, 8);
      if (!(lane & 12)){
        u64 pk = (u64)p | ((u64)q << 32);
        __hip_atomic_store((u64*)(W1 + hst), pk,
                           __ATOMIC_RELAXED, __HIP_MEMORY_SCOPE_AGENT);
        // archive for fc: [t][128 rows][1KB]
        __hip_atomic_store((u64*)(HS + (((s-1)<<7) + b0 + row_c)*1024 + cg*32 + (w<<3)), pk,
                           __ATOMIC_RELAXED, __HIP_MEMORY_SCOPE_AGENT);
      }
    }
    gbar(flags, g, cg, tid, ++bt);
  }

  // single acquire fence: invalidate stale cached lines before plain HS reads
  __builtin_amdgcn_fence(__ATOMIC_ACQUIRE, "agent");
  __syncthreads();

  // ================= fc epilogue =================
  for (int qd = tid; qd < 8192; qd += 256){      // fcW [64][512] f32 -> f16 LDS
    int i = qd >> 7, kq = qd & 127;
    float4 v = *(const float4*)(fcW + (i<<9) + (kq<<2));
    f16* p = (f16*)(lds + (i<<10) + (kq<<3));
    p[0]=(f16)v.x; p[1]=(f16)v.y; p[2]=(f16)v.z; p[3]=(f16)v.w;
  }
  __syncthreads();
  {
    int t  = (cg<<2) + w;                        // 32 cg x 4 waves = 128 timesteps
    int r  = (lane >> 2) & 15;
    int iq = lane & 3;
    const char* hsrow = HS + (((t<<7) + b0 + r)<<10);
    float acc[16];
#pragma unroll
    for (int ii = 0; ii < 16; ++ii) acc[ii] = 0.f;
    for (int k8 = 0; k8 < 64; ++k8){
      f16x8 hv = *(const f16x8*)(hsrow + (k8<<4));
#pragma unroll
      for (int ii = 0; ii < 16; ++ii){
        f16x8 wv = *(const f16x8*)(lds + (((iq<<4)+ii)<<10) + (k8<<4));
#pragma unroll
        for (int jj = 0; jj < 8; ++jj) acc[ii] += (float)hv[jj] * (float)wv[jj];
      }
    }
#pragma unroll
    for (int ii = 0; ii < 16; ++ii){
      int i = (iq<<4) + ii;
      out[((((b0+r)<<7) + t)<<6) + i] = acc[ii] + fcb[i];
    }
  }
}

extern "C" void kernel_launch(void* const* d_in, const int* in_sizes, int n_in,
                              void* d_out, int out_size, void* d_ws, size_t ws_size,
                              hipStream_t stream){
  const float* x     = (const float*)d_in[0];
  const float* eWih0 = (const float*)d_in[1];
  const float* eWhh0 = (const float*)d_in[2];
  const float* ebi0  = (const float*)d_in[3];
  const float* ebh0  = (const float*)d_in[4];
  const float* eWih1 = (const float*)d_in[5];
  const float* eWhh1 = (const float*)d_in[6];
  const float* ebi1  = (const float*)d_in[7];
  const float* ebh1  = (const float*)d_in[8];
  const float* dWih0 = (const float*)d_in[9];
  const float* dWhh0 = (const float*)d_in[10];
  const float* dbi0  = (const float*)d_in[11];
  const float* dbh0  = (const float*)d_in[12];
  const float* dWih1 = (const float*)d_in[13];
  const float* dWhh1 = (const float*)d_in[14];
  const float* dbi1  = (const float*)d_in[15];
  const float* dbh1  = (const float*)d_in[16];
  const float* fcW   = (const float*)d_in[17];
  const float* fcb   = (const float*)d_in[18];
  char* ws = (char*)d_ws;

  hipMemsetAsync(d_ws, 0, OFF_XH, stream);       // zero flags + all h double-buffers
  cvt_x<<<256, 256, 0, stream>>>(x, ws);
  lstm_persist<<<256, 256, 0, stream>>>(eWih0,eWhh0,ebi0,ebh0,eWih1,eWhh1,ebi1,ebh1,
                                        dWih0,dWhh0,dbi0,dbh0,dWih1,dWhh1,dbi1,dbh1,
                                        fcW,fcb,(float*)d_out,ws);
}

// Round 7
// 1386.461 us; speedup vs baseline: 3.5510x; 1.1056x over previous
//
#include <hip/hip_runtime.h>
#include <cstdint>

#define TT 128

typedef _Float16 f16;
typedef _Float16 f16x8 __attribute__((ext_vector_type(8)));
typedef float f32x4 __attribute__((ext_vector_type(4)));
typedef unsigned int u32;
typedef unsigned long long u64;

// pin a value into VGPRs: asm outputs are not rematerializable, so the
// compiler must keep it live instead of re-loading/re-converting per step.
#define PIN(v) asm volatile("" : "+v"(v))

// ---- workspace layout (bytes) ----
// [0, 512): 8 per-group arrival counters, one per 64B line
#define OFF_H0    16384                 // h slabs: [2 par][8 g][32 cg][16 row][32B] = 256KB
#define OFF_H1    (OFF_H0 + 262144)
#define OFF_D0    (OFF_H1 + 262144)
#define OFF_D1    (OFF_D0 + 262144)
#define OFF_XH    (OFF_D1 + 262144)     // x f16: [T][8 g][16 row][128B] = 2MB
#define OFF_HS    (OFF_XH + 2097152)    // dec out: [T][128 row][1KB] = 16MB

// ---- LDS ----
#define L_SA   0          // h0 slab staged: [32 cg][16 row][48B] = 24576
#define L_SB   24576      // h1 slab staged
#define L_TOT  65536      // fc overlay [64][1024B] needs 64KB

#define MFMA16(a,b,c) __builtin_amdgcn_mfma_f32_16x16x32_f16((a),(b),(c),0,0,0)

__device__ __forceinline__ float sigm(float x){ return 1.f/(1.f+__expf(-x)); }
__device__ __forceinline__ float tanhft(float x){ return 1.f - 2.f/(__expf(2.f*x)+1.f); }

// one B-fragment (8 f16 along K at gate-row srow) from fp32 weights (one-time load)
__device__ __forceinline__ f16x8 wfrag(const float* __restrict__ src, int K, int srow,
                                       int k, int j){
  const float* p = src + srow*K + (k<<5) + (j<<3);
  float4 v0 = *(const float4*)p;
  float4 v1 = *(const float4*)(p+4);
  f16x8 r;
  r[0]=(f16)v0.x; r[1]=(f16)v0.y; r[2]=(f16)v0.z; r[3]=(f16)v0.w;
  r[4]=(f16)v1.x; r[5]=(f16)v1.y; r[6]=(f16)v1.z; r[7]=(f16)v1.w;
  return r;
}

// stage one 16KB h slab (global [32cg][16row][32B], written by agent atomics) into
// LDS [32cg][16row][48B] via agent-relaxed atomic b64 loads (coherent, no fence).
__device__ __forceinline__ void stage1(const char* R, char* S, int tid){
  const int cgs = tid >> 3, rr = (tid & 7) << 1;
  const char* gp = R + cgs*512 + rr*32;
  char* sp = S + cgs*768 + rr*48;
  u64 t0[8];
#pragma unroll
  for (int e = 0; e < 2; ++e)
#pragma unroll
    for (int i = 0; i < 4; ++i)
      t0[e*4+i] = __hip_atomic_load((const u64*)(gp + e*32 + i*8),
                                    __ATOMIC_RELAXED, __HIP_MEMORY_SCOPE_AGENT);
#pragma unroll
  for (int e = 0; e < 2; ++e)
#pragma unroll
    for (int i = 0; i < 4; ++i)
      *(u64*)(sp + e*48 + i*8) = t0[e*4+i];
}

__device__ __forceinline__ void stage2(const char* R0, const char* R1,
                                       char* SA, char* SB, int tid){
  const int cgs = tid >> 3, rr = (tid & 7) << 1;
  const char* g0 = R0 + cgs*512 + rr*32;
  const char* g1 = R1 + cgs*512 + rr*32;
  char* s0 = SA + cgs*768 + rr*48;
  char* s1 = SB + cgs*768 + rr*48;
  u64 t0[8], t1[8];
#pragma unroll
  for (int e = 0; e < 2; ++e)
#pragma unroll
    for (int i = 0; i < 4; ++i)
      t0[e*4+i] = __hip_atomic_load((const u64*)(g0 + e*32 + i*8),
                                    __ATOMIC_RELAXED, __HIP_MEMORY_SCOPE_AGENT);
#pragma unroll
  for (int e = 0; e < 2; ++e)
#pragma unroll
    for (int i = 0; i < 4; ++i)
      t1[e*4+i] = __hip_atomic_load((const u64*)(g1 + e*32 + i*8),
                                    __ATOMIC_RELAXED, __HIP_MEMORY_SCOPE_AGENT);
#pragma unroll
  for (int e = 0; e < 2; ++e)
#pragma unroll
    for (int i = 0; i < 4; ++i)
      *(u64*)(s0 + e*48 + i*8) = t0[e*4+i];
#pragma unroll
  for (int e = 0; e < 2; ++e)
#pragma unroll
    for (int i = 0; i < 4; ++i)
      *(u64*)(s1 + e*48 + i*8) = t1[e*4+i];
}

// group barrier (32 WGs) via single-line monotonic counter:
// syncthreads drains vmcnt (h atomic stores at LLC) -> tid0 atomic_add(+1) ->
// tid0 polls ONE line until count >= 32*step -> syncthreads. No fences:
// data reads are agent-scope atomics (coherent by construction).
__device__ __forceinline__ void gbar(u32* cnt, int tid, u32 target32){
  __syncthreads();
  if (tid == 0){
    u32 c = __hip_atomic_fetch_add(cnt, 1, __ATOMIC_RELAXED, __HIP_MEMORY_SCOPE_AGENT) + 1;
    while (c < target32){
      __builtin_amdgcn_s_sleep(1);
      c = __hip_atomic_load(cnt, __ATOMIC_RELAXED, __HIP_MEMORY_SCOPE_AGENT);
    }
  }
  __syncthreads();
}

// x [B][T][64] f32 -> [T][g 8][row 16][128B] f16
__global__ void cvt_x(const float* __restrict__ x, char* __restrict__ ws){
  int i = blockIdx.x*256 + threadIdx.x;          // 65536 threads, 16 f32 each
  int p = i & 3, b = (i >> 2) & 127, t = i >> 9;
  const float* s = x + (((b<<7) + t)<<6) + (p<<4);
  float4 v0 = *(const float4*)s,     v1 = *(const float4*)(s+4);
  float4 v2 = *(const float4*)(s+8), v3 = *(const float4*)(s+12);
  f16x8 h0, h1;
  h0[0]=(f16)v0.x; h0[1]=(f16)v0.y; h0[2]=(f16)v0.z; h0[3]=(f16)v0.w;
  h0[4]=(f16)v1.x; h0[5]=(f16)v1.y; h0[6]=(f16)v1.z; h0[7]=(f16)v1.w;
  h1[0]=(f16)v2.x; h1[1]=(f16)v2.y; h1[2]=(f16)v2.z; h1[3]=(f16)v2.w;
  h1[4]=(f16)v3.x; h1[5]=(f16)v3.y; h1[6]=(f16)v3.z; h1[7]=(f16)v3.w;
  char* d = ws + OFF_XH + ((((t<<3) + (b>>4))<<4) + (b&15))*128 + (p<<5);
  *(f16x8*)d = h0;
  *(f16x8*)(d+16) = h1;
}

__global__ __launch_bounds__(256, 1) void lstm_persist(
    const float* __restrict__ eWih0, const float* __restrict__ eWhh0,
    const float* __restrict__ ebi0,  const float* __restrict__ ebh0,
    const float* __restrict__ eWih1, const float* __restrict__ eWhh1,
    const float* __restrict__ ebi1,  const float* __restrict__ ebh1,
    const float* __restrict__ dWih0, const float* __restrict__ dWhh0,
    const float* __restrict__ dbi0,  const float* __restrict__ dbh0,
    const float* __restrict__ dWih1, const float* __restrict__ dWhh1,
    const float* __restrict__ dbi1,  const float* __restrict__ dbh1,
    const float* __restrict__ fcW,   const float* __restrict__ fcb,
    float* __restrict__ out, char* __restrict__ ws)
{
  __shared__ __align__(16) char lds[L_TOT];
  const int tid  = threadIdx.x;
  const int wg   = blockIdx.x;
  const int g    = wg & 7;             // batch group (16 rows)
  const int cg   = wg >> 3;            // column group (16 hcols = 64 gate cols)
  const int b0   = g << 4;
  const int lane = tid & 63, w = tid >> 6;
  const int j    = lane >> 4;                    // k-run (0..3)
  const int arow = lane & 15;                    // A row
  const int bq   = lane & 15;                    // B row: (hc local = bq>>2, gate = bq&3)
  const int srow = ((bq&3)<<9) + (cg<<4) + (w<<2) + (bq>>2);   // global gate row
  const int lq   = lane & 3;
  const int hcc  = (lane >> 2) & 3;              // cell hcol within wave quad-group
  const int row_c = ((lane>>4)<<2) + lq;         // cell-owned batch row (0..15)

  u32* cnt = (u32*)(ws + (g<<6));                // one counter line per group
  char* H0 = ws + OFF_H0;  char* H1 = ws + OFF_H1;
  char* D0 = ws + OFF_D0;  char* D1 = ws + OFF_D1;
  const char* XH = ws + OFF_XH;
  char* HS = ws + OFF_HS;
  char* SA = lds + 0; char* SB = lds + L_SB;

  // A-frag LDS base: [cg' = kk*2 + (j>>1)][arow][(j&1)*16], strides 768/48
  const int abase = ((j>>1)*768) + arow*48 + ((j&1)<<4);
  // h store offset within slab: [cg][row][32B], wave piece at w*8
  const int hst = cg*512 + row_c*32 + (w<<3);

  // ---- encoder weights -> registers, PINNED (one-time load+cvt) ----
  f16x8 wA[16], wB[16], wC[16], wX0, wX1;
#pragma unroll
  for (int k = 0; k < 16; ++k){
    wA[k] = wfrag(eWhh0, 512, srow, k, j);  PIN(wA[k]);
    wB[k] = wfrag(eWih1, 512, srow, k, j);  PIN(wB[k]);
    wC[k] = wfrag(eWhh1, 512, srow, k, j);  PIN(wC[k]);
  }
  wX0 = wfrag(eWih0, 64, srow, 0, j);  PIN(wX0);
  wX1 = wfrag(eWih0, 64, srow, 1, j);  PIN(wX1);
  float B0r[4], B1r[4];
#pragma unroll
  for (int e = 0; e < 4; ++e){
    int bi = (e<<9) + (cg<<4) + (w<<2) + hcc;
    B0r[e] = ebi0[bi] + ebh0[bi];  PIN(B0r[e]);
    B1r[e] = ebi1[bi] + ebh1[bi];  PIN(B1r[e]);
  }

  // quad 4x4 transpose: a[r]=preact(col=(hcc,gate) of this lane, row rg*4+r)
  // -> t[e]=preact(gate e, hcc, row rg*4+lq)
  auto qtr = [&](f32x4 a) -> f32x4 {
    float s0 = __shfl_xor(a[1],1), s1 = __shfl_xor(a[0],1);
    float s2 = __shfl_xor(a[3],1), s3 = __shfl_xor(a[2],1);
    bool o1 = lane & 1;
    float c0 = o1 ? s0 : a[0];
    float c1 = o1 ? a[1] : s1;
    float c2 = o1 ? s2 : a[2];
    float c3 = o1 ? a[3] : s3;
    float u0 = __shfl_xor(c2,2), u1 = __shfl_xor(c3,2);
    float u2 = __shfl_xor(c0,2), u3 = __shfl_xor(c1,2);
    bool o2 = lane & 2;
    f32x4 t;
    t[0] = o2 ? u0 : c0;
    t[1] = o2 ? u1 : c1;
    t[2] = o2 ? c2 : u2;
    t[3] = o2 ? c3 : u3;
    return t;
  };

  float c0v = 0.f, c1v = 0.f;
  u32 bt = 0;

  // ================= encoder: layers 0+1 pipelined, 1 barrier/step =================
  for (int s = 0; s <= TT; ++s){
    const bool d0 = (s < TT), d1 = (s >= 1);
    const char* R0 = H0 + (((s&1)<<3) + g)*16384;
    const char* R1 = H1 + (((s&1)<<3) + g)*16384;
    char* W0 = H0 + ((((s+1)&1)<<3) + g)*16384;
    char* W1 = H1 + ((((s+1)&1)<<3) + g)*16384;

    stage2(R0, R1, SA, SB, tid);      // coherent atomic loads -> LDS
    f16x8 xa0, xa1;
    if (d0){
      const char* xg = XH + (((s<<3) + g)<<11) + arow*128 + (j<<4);
      xa0 = *(const f16x8*)(xg);       // plain cached loads (x is read-only)
      xa1 = *(const f16x8*)(xg + 64);
    }
    __syncthreads();

    f32x4 acc0 = {0.f,0.f,0.f,0.f}, acc1 = {0.f,0.f,0.f,0.f};
    if (d0){
      acc0 = MFMA16(xa0, wX0, acc0);
      acc0 = MFMA16(xa1, wX1, acc0);
    }
#pragma unroll
    for (int k = 0; k < 16; ++k){
      f16x8 a0 = *(const f16x8*)(SA + k*1536 + abase);   // h0 serves BOTH layers
      f16x8 a1 = *(const f16x8*)(SB + k*1536 + abase);
      acc0 = MFMA16(a0, wA[k], acc0);
      acc1 = MFMA16(a0, wB[k], acc1);
      acc1 = MFMA16(a1, wC[k], acc1);
    }

    if (d0){
      f32x4 t = qtr(acc0);
      float gi = sigm(t[0]+B0r[0]), gf = sigm(t[1]+B0r[1]);
      float gg = tanhft(t[2]+B0r[2]), go = sigm(t[3]+B0r[3]);
      c0v = gf*c0v + gi*gg;
      float h = go * tanhft(c0v);
      union { f16 hf; unsigned short su; } cv; cv.hf = (f16)h;
      u32 v = cv.su;
      u32 p = v | (((u32)(unsigned short)__shfl_xor((int)v, 4)) << 16);
      u32 q = (u32)__shfl_xor((int)p, 8);
      if (!(lane & 12)){
        u64 pk = (u64)p | ((u64)q << 32);
        __hip_atomic_store((u64*)(W0 + hst), pk,
                           __ATOMIC_RELAXED, __HIP_MEMORY_SCOPE_AGENT);
      }
    }
    if (d1){
      f32x4 t = qtr(acc1);
      float gi = sigm(t[0]+B1r[0]), gf = sigm(t[1]+B1r[1]);
      float gg = tanhft(t[2]+B1r[2]), go = sigm(t[3]+B1r[3]);
      c1v = gf*c1v + gi*gg;
      float h = go * tanhft(c1v);
      union { f16 hf; unsigned short su; } cv; cv.hf = (f16)h;
      u32 v = cv.su;
      u32 p = v | (((u32)(unsigned short)__shfl_xor((int)v, 4)) << 16);
      u32 q = (u32)__shfl_xor((int)p, 8);
      if (!(lane & 12)){
        u64 pk = (u64)p | ((u64)q << 32);
        __hip_atomic_store((u64*)(W1 + hst), pk,
                           __ATOMIC_RELAXED, __HIP_MEMORY_SCOPE_AGENT);
      }
    }
    gbar(cnt, tid, (++bt) << 5);
  }

  // ================= zx = z @ dW_ih0 + biases (one-time) =================
  f32x4 zx;
  {
    stage1(H1 + (8 + g)*16384, SA, tid);        // z = final enc1 h, parity 1
    f16x8 wZ[16];
#pragma unroll
    for (int k = 0; k < 16; ++k) wZ[k] = wfrag(dWih0, 512, srow, k, j);
    float zb = dbi0[srow] + dbh0[srow];
    zx[0]=zb; zx[1]=zb; zx[2]=zb; zx[3]=zb;
    __syncthreads();
#pragma unroll
    for (int k = 0; k < 16; ++k)
      zx = MFMA16(*(const f16x8*)(SA + k*1536 + abase), wZ[k], zx);
  }

  // ---- decoder weights -> registers, PINNED ----
#pragma unroll
  for (int k = 0; k < 16; ++k){
    wA[k] = wfrag(dWhh0, 512, srow, k, j);  PIN(wA[k]);
    wB[k] = wfrag(dWih1, 512, srow, k, j);  PIN(wB[k]);
    wC[k] = wfrag(dWhh1, 512, srow, k, j);  PIN(wC[k]);
  }
#pragma unroll
  for (int e = 0; e < 4; ++e){
    int bi = (e<<9) + (cg<<4) + (w<<2) + hcc;
    B1r[e] = dbi1[bi] + dbh1[bi];  PIN(B1r[e]);
  }
  c0v = 0.f; c1v = 0.f;

  // ================= decoder =================
  for (int s = 0; s <= TT; ++s){
    const bool d0 = (s < TT), d1 = (s >= 1);
    const char* R0 = D0 + (((s&1)<<3) + g)*16384;
    const char* R1 = D1 + (((s&1)<<3) + g)*16384;
    char* W0 = D0 + ((((s+1)&1)<<3) + g)*16384;
    char* W1 = D1 + ((((s+1)&1)<<3) + g)*16384;

    stage2(R0, R1, SA, SB, tid);
    __syncthreads();

    f32x4 acc0 = zx, acc1 = {0.f,0.f,0.f,0.f};
#pragma unroll
    for (int k = 0; k < 16; ++k){
      f16x8 a0 = *(const f16x8*)(SA + k*1536 + abase);
      f16x8 a1 = *(const f16x8*)(SB + k*1536 + abase);
      acc0 = MFMA16(a0, wA[k], acc0);
      acc1 = MFMA16(a0, wB[k], acc1);
      acc1 = MFMA16(a1, wC[k], acc1);
    }

    if (d0){
      f32x4 t = qtr(acc0);
      float gi = sigm(t[0]), gf = sigm(t[1]);    // biases folded into zx
      float gg = tanhft(t[2]), go = sigm(t[3]);
      c0v = gf*c0v + gi*gg;
      float h = go * tanhft(c0v);
      union { f16 hf; unsigned short su; } cv; cv.hf = (f16)h;
      u32 v = cv.su;
      u32 p = v | (((u32)(unsigned short)__shfl_xor((int)v, 4)) << 16);
      u32 q = (u32)__shfl_xor((int)p, 8);
      if (!(lane & 12)){
        u64 pk = (u64)p | ((u64)q << 32);
        __hip_atomic_store((u64*)(W0 + hst), pk,
                           __ATOMIC_RELAXED, __HIP_MEMORY_SCOPE_AGENT);
      }
    }
    if (d1){
      f32x4 t = qtr(acc1);
      float gi = sigm(t[0]+B1r[0]), gf = sigm(t[1]+B1r[1]);
      float gg = tanhft(t[2]+B1r[2]), go = sigm(t[3]+B1r[3]);
      c1v = gf*c1v + gi*gg;
      float h = go * tanhft(c1v);
      union { f16 hf; unsigned short su; } cv; cv.hf = (f16)h;
      u32 v = cv.su;
      u32 p = v | (((u32)(unsigned short)__shfl_xor((int)v, 4)) << 16);
      u32 q = (u32)__shfl_xor((int)p, 8);
      if (!(lane & 12)){
        u64 pk = (u64)p | ((u64)q << 32);
        __hip_atomic_store((u64*)(W1 + hst), pk,
                           __ATOMIC_RELAXED, __HIP_MEMORY_SCOPE_AGENT);
        // archive for fc: [t][128 rows][1KB]
        __hip_atomic_store((u64*)(HS + (((s-1)<<7) + b0 + row_c)*1024 + cg*32 + (w<<3)), pk,
                           __ATOMIC_RELAXED, __HIP_MEMORY_SCOPE_AGENT);
      }
    }
    gbar(cnt, tid, (++bt) << 5);
  }

  // single acquire fence: invalidate stale cached lines before plain HS reads
  __builtin_amdgcn_fence(__ATOMIC_ACQUIRE, "agent");
  __syncthreads();

  // ================= fc epilogue =================
  for (int qd = tid; qd < 8192; qd += 256){      // fcW [64][512] f32 -> f16 LDS
    int i = qd >> 7, kq = qd & 127;
    float4 v = *(const float4*)(fcW + (i<<9) + (kq<<2));
    f16* p = (f16*)(lds + (i<<10) + (kq<<3));
    p[0]=(f16)v.x; p[1]=(f16)v.y; p[2]=(f16)v.z; p[3]=(f16)v.w;
  }
  __syncthreads();
  {
    int t  = (cg<<2) + w;                        // 32 cg x 4 waves = 128 timesteps
    int r  = (lane >> 2) & 15;
    int iq = lane & 3;
    const char* hsrow = HS + (((t<<7) + b0 + r)<<10);
    float acc[16];
#pragma unroll
    for (int ii = 0; ii < 16; ++ii) acc[ii] = 0.f;
    for (int k8 = 0; k8 < 64; ++k8){
      f16x8 hv = *(const f16x8*)(hsrow + (k8<<4));
#pragma unroll
      for (int ii = 0; ii < 16; ++ii){
        f16x8 wv = *(const f16x8*)(lds + (((iq<<4)+ii)<<10) + (k8<<4));
#pragma unroll
        for (int jj = 0; jj < 8; ++jj) acc[ii] += (float)hv[jj] * (float)wv[jj];
      }
    }
#pragma unroll
    for (int ii = 0; ii < 16; ++ii){
      int i = (iq<<4) + ii;
      out[((((b0+r)<<7) + t)<<6) + i] = acc[ii] + fcb[i];
    }
  }
}

extern "C" void kernel_launch(void* const* d_in, const int* in_sizes, int n_in,
                              void* d_out, int out_size, void* d_ws, size_t ws_size,
                              hipStream_t stream){
  const float* x     = (const float*)d_in[0];
  const float* eWih0 = (const float*)d_in[1];
  const float* eWhh0 = (const float*)d_in[2];
  const float* ebi0  = (const float*)d_in[3];
  const float* ebh0  = (const float*)d_in[4];
  const float* eWih1 = (const float*)d_in[5];
  const float* eWhh1 = (const float*)d_in[6];
  const float* ebi1  = (const float*)d_in[7];
  const float* ebh1  = (const float*)d_in[8];
  const float* dWih0 = (const float*)d_in[9];
  const float* dWhh0 = (const float*)d_in[10];
  const float* dbi0  = (const float*)d_in[11];
  const float* dbh0  = (const float*)d_in[12];
  const float* dWih1 = (const float*)d_in[13];
  const float* dWhh1 = (const float*)d_in[14];
  const float* dbi1  = (const float*)d_in[15];
  const float* dbh1  = (const float*)d_in[16];
  const float* fcW   = (const float*)d_in[17];
  const float* fcb   = (const float*)d_in[18];
  char* ws = (char*)d_ws;

  hipMemsetAsync(d_ws, 0, OFF_XH, stream);       // zero counters + all h double-buffers
  cvt_x<<<256, 256, 0, stream>>>(x, ws);
  lstm_persist<<<256, 256, 0, stream>>>(eWih0,eWhh0,ebi0,ebh0,eWih1,eWhh1,ebi1,ebh1,
                                        dWih0,dWhh0,dbi0,dbh0,dWih1,dWhh1,dbi1,dbh1,
                                        fcW,fcb,(float*)d_out,ws);
}